// Round 1
// baseline (3124.090 us; speedup 1.0000x reference)
//
#include <hip/hip_runtime.h>

#define DD 128      // GNN_DIM == NODE_FEAT
#define HDIM 512    // H * D
#define EFEAT 32
#define NHEAD 4

__device__ __forceinline__ float lrelu(float x){ return x > 0.f ? x : 0.2f*x; }

__device__ __forceinline__ float waveReduceSum(float v){
  #pragma unroll
  for (int m = 1; m < 64; m <<= 1) v += __shfl_xor(v, m, 64);
  return v;
}

// ---------------- edge-attr mean (sum, divided later) ----------------
__global__ void ea_sum_kernel(const float* __restrict__ ea, float* __restrict__ ea_sum, int E){
  __shared__ float s[EFEAT];
  int t = threadIdx.x;
  if (t < EFEAT) s[t] = 0.f;
  __syncthreads();
  int f = t & 31;
  int g = t >> 5;                 // 8 edge groups per block
  float acc = 0.f;
  for (int e = blockIdx.x*8 + g; e < E; e += gridDim.x*8)
    acc += ea[(size_t)e*EFEAT + f];
  atomicAdd(&s[f], acc);
  __syncthreads();
  if (t < EFEAT) atomicAdd(&ea_sum[t], s[t]);
}

// ---------------- CSR build over dst ----------------
__global__ void hist_kernel(const int* __restrict__ dst, int* __restrict__ deg, int E){
  int e = blockIdx.x*blockDim.x + threadIdx.x;
  if (e < E) atomicAdd(&deg[dst[e]], 1);
}

__global__ void scan_kernel(const int* __restrict__ deg, int* __restrict__ offs, int N){
  __shared__ int s[1024];
  __shared__ int carry;
  int t = threadIdx.x;
  if (t == 0) carry = 0;
  __syncthreads();
  for (int base = 0; base < N; base += 1024){
    int i = base + t;
    int v = (i < N) ? deg[i] : 0;
    s[t] = v;
    __syncthreads();
    for (int d = 1; d < 1024; d <<= 1){
      int x = (t >= d) ? s[t-d] : 0;
      __syncthreads();
      s[t] += x;
      __syncthreads();
    }
    int incl = s[t];
    int c = carry;
    if (i < N) offs[i] = c + incl - v;
    __syncthreads();
    if (t == 1023) carry = c + s[1023];
    __syncthreads();
  }
  if (t == 0) offs[N] = carry;
}

__global__ void scatter_kernel(const int* __restrict__ dst, int* __restrict__ cursor,
                               int* __restrict__ eid, int E){
  int e = blockIdx.x*blockDim.x + threadIdx.x;
  if (e < E){
    int p = atomicAdd(&cursor[dst[e]], 1);
    eid[p] = e;
  }
}

// ---------------- fold attention vectors into W (all layers) ----------------
// ws_att[l][k][j] (j<4: src-head j, j>=4: dst-head j-4)
// we_att[l][f][h], al_self[l][h]
__global__ void fold_kernel(const float* __restrict__ gat_W, const float* __restrict__ att_src,
                            const float* __restrict__ att_dst, const float* __restrict__ gat_We,
                            const float* __restrict__ att_edge, const float* __restrict__ ea_sum,
                            float invE, float* __restrict__ ws_att, float* __restrict__ we_att,
                            float* __restrict__ al_self, int L){
  __shared__ float swe[6*EFEAT*NHEAD];
  int t = threadIdx.x;
  for (int idx = t; idx < L*DD*8; idx += 256){
    int j = idx & 7; int k = (idx >> 3) & 127; int l = idx >> 10;
    int h = j & 3;
    const float* att = (j < 4) ? att_src : att_dst;
    const float* Wl = gat_W + (size_t)l*DD*HDIM;
    const float* av = att + (size_t)(l*NHEAD + h)*DD;
    float acc = 0.f;
    for (int d = 0; d < DD; d++) acc += Wl[(size_t)k*HDIM + h*DD + d] * av[d];
    ws_att[idx] = acc;
  }
  for (int idx = t; idx < L*EFEAT*NHEAD; idx += 256){
    int h = idx & 3; int f = (idx >> 2) & 31; int l = idx >> 7;
    const float* Wel = gat_We + (size_t)l*EFEAT*HDIM;
    const float* av = att_edge + (size_t)(l*NHEAD + h)*DD;
    float acc = 0.f;
    for (int d = 0; d < DD; d++) acc += Wel[(size_t)f*HDIM + h*DD + d] * av[d];
    we_att[idx] = acc;
    swe[idx] = acc;
  }
  __syncthreads();
  for (int idx = t; idx < L*NHEAD; idx += 256){
    int h = idx & 3; int l = idx >> 2;
    float acc = 0.f;
    for (int f = 0; f < EFEAT; f++) acc += ea_sum[f]*invE * swe[(l*EFEAT + f)*NHEAD + h];
    al_self[idx] = acc;
  }
}

// ---------------- generic fp32 linear: C[M,NOUT] = A[M,128] @ W[128,NOUT] (+bias) ----------------
template<int NOUT>
__global__ __launch_bounds__(256) void linear_kernel(const float* __restrict__ A,
    const float* __restrict__ W, const float* __restrict__ bias,
    float* __restrict__ C, int M, int do_relu){
  constexpr int TM = (NOUT == 512) ? 32 : 64;
  __shared__ float As[TM][DD];
  int t = threadIdx.x;
  int row0 = blockIdx.x*TM;
  for (int i = t; i < TM*DD; i += 256){
    int r = i >> 7, k = i & 127;
    int gr = row0 + r;
    As[r][k] = (gr < M) ? A[(size_t)gr*DD + k] : 0.f;
  }
  __syncthreads();
  int col, rbase;
  if constexpr (NOUT == 512){ col = t; rbase = 0; }
  else { col = t & 127; rbase = (t >> 7)*32; }
  float acc0[32]; float acc1[32];
  #pragma unroll
  for (int r = 0; r < 32; r++){ acc0[r] = 0.f; acc1[r] = 0.f; }
  #pragma unroll 4
  for (int k = 0; k < DD; k++){
    float w0 = W[(size_t)k*NOUT + col];
    float w1 = 0.f;
    if constexpr (NOUT == 512) w1 = W[(size_t)k*NOUT + col + 256];
    #pragma unroll
    for (int r = 0; r < 32; r++){
      float a = As[rbase + r][k];
      acc0[r] += a*w0;
      if constexpr (NOUT == 512) acc1[r] += a*w1;
    }
  }
  float b0 = bias ? bias[col] : 0.f;
  float b1 = 0.f;
  if constexpr (NOUT == 512){ if (bias) b1 = bias[col + 256]; }
  for (int r = 0; r < 32; r++){
    int row = row0 + rbase + r;
    if (row < M){
      float v0 = acc0[r] + b0;
      if (do_relu) v0 = fmaxf(v0, 0.f);
      C[(size_t)row*NOUT + col] = v0;
      if constexpr (NOUT == 512){
        float v1 = acc1[r] + b1;
        if (do_relu) v1 = fmaxf(v1, 0.f);
        C[(size_t)row*NOUT + col + 256] = v1;
      }
    }
  }
}

// ---------------- fused LayerNorm + FiLM + attention-logit projection ----------------
__global__ __launch_bounds__(256) void ln_film_al_kernel(const float* __restrict__ h,
    const float* __restrict__ ln_scale, const float* __restrict__ ln_bias,
    const float* __restrict__ gamma, const float* __restrict__ beta,
    const float* __restrict__ ws_att,   // [128][8] this layer
    float* __restrict__ hm, float* __restrict__ al_s, float* __restrict__ al_d, int N){
  __shared__ float s_att[DD*8];
  int t = threadIdx.x;
  for (int i = t; i < DD*8; i += 256) s_att[i] = ws_att[i];
  __syncthreads();
  int wave = t >> 6, lane = t & 63;
  int n = blockIdx.x*4 + wave;
  if (n >= N) return;
  int e0 = lane, e1 = lane + 64;
  float v0 = h[(size_t)n*DD + e0], v1 = h[(size_t)n*DD + e1];
  float sum = waveReduceSum(v0 + v1);
  float mu = sum * (1.f/128.f);
  float d0 = v0 - mu, d1 = v1 - mu;
  float vs = waveReduceSum(d0*d0 + d1*d1);
  float rstd = rsqrtf(vs*(1.f/128.f) + 1e-5f);
  float hn0 = d0*rstd*ln_scale[e0] + ln_bias[e0];
  float hn1 = d1*rstd*ln_scale[e1] + ln_bias[e1];
  float m0 = gamma[e0]*hn0 + beta[e0];
  float m1 = gamma[e1]*hn1 + beta[e1];
  hm[(size_t)n*DD + e0] = m0;
  hm[(size_t)n*DD + e1] = m1;
  #pragma unroll
  for (int j = 0; j < 8; j++){
    float a = m0*s_att[e0*8 + j] + m1*s_att[e1*8 + j];
    a = waveReduceSum(a);
    if (lane == 0){
      if (j < 4) al_s[n*4 + j] = a;
      else       al_d[n*4 + (j - 4)] = a;
    }
  }
}

// ---------------- per-edge attention logits for one layer ----------------
__global__ __launch_bounds__(256) void al_edge_kernel(const float* __restrict__ ea,
    const float* __restrict__ we_att,   // [32][4] this layer
    float* __restrict__ al_e, int E){
  __shared__ float sea[256][EFEAT + 1];
  __shared__ float swe[EFEAT*NHEAD];
  int t = threadIdx.x;
  if (t < EFEAT*NHEAD) swe[t] = we_att[t];
  int e0 = blockIdx.x*256;
  for (int i = t; i < 256*EFEAT; i += 256){
    int e = i >> 5, f = i & 31;
    sea[e][f] = (e0 + e < E) ? ea[(size_t)(e0 + e)*EFEAT + f] : 0.f;
  }
  __syncthreads();
  int e = e0 + t;
  if (e < E){
    float a0 = 0.f, a1 = 0.f, a2 = 0.f, a3 = 0.f;
    #pragma unroll
    for (int f = 0; f < EFEAT; f++){
      float x = sea[t][f];
      a0 += x*swe[f*4 + 0]; a1 += x*swe[f*4 + 1];
      a2 += x*swe[f*4 + 2]; a3 += x*swe[f*4 + 3];
    }
    al_e[(size_t)e*4 + 0] = a0; al_e[(size_t)e*4 + 1] = a1;
    al_e[(size_t)e*4 + 2] = a2; al_e[(size_t)e*4 + 3] = a3;
  }
}

// ---------------- GAT aggregation, one block per node ----------------
__global__ __launch_bounds__(256) void aggregate_kernel(
    const float* __restrict__ xfeat, const float* __restrict__ al_s,
    const float* __restrict__ al_d, const float* __restrict__ al_e,
    const float* __restrict__ al_self,                 // [4] this layer
    const int* __restrict__ offs, const int* __restrict__ eid,
    const int* __restrict__ srcA, const float* __restrict__ bias,  // gat_bias layer
    float* __restrict__ hOut, int N){
  int n = blockIdx.x;
  int t = threadIdx.x;
  int d = t & 127, hp = t >> 7;
  int h0 = hp, h1 = hp + 2;
  int ch0 = h0*DD + d, ch1 = h1*DD + d;
  int beg = offs[n], end = offs[n + 1];
  float ald0 = al_d[(size_t)n*4 + h0], ald1 = al_d[(size_t)n*4 + h1];
  float aself0 = lrelu(al_s[(size_t)n*4 + h0] + ald0 + al_self[h0]);
  float aself1 = lrelu(al_s[(size_t)n*4 + h1] + ald1 + al_self[h1]);
  // phase A: per-head max over incoming edges (+ self loop)
  float m0 = aself0, m1 = aself1;
  for (int p = beg; p < end; p++){
    int e = eid[p]; int s = srcA[e];
    float a0 = lrelu(al_s[(size_t)s*4 + h0] + ald0 + al_e[(size_t)e*4 + h0]);
    float a1 = lrelu(al_s[(size_t)s*4 + h1] + ald1 + al_e[(size_t)e*4 + h1]);
    m0 = fmaxf(m0, a0); m1 = fmaxf(m1, a1);
  }
  // phase B: exp-weighted accumulation
  float w0 = __expf(aself0 - m0), w1 = __expf(aself1 - m1);
  float acc0 = w0 * xfeat[(size_t)n*HDIM + ch0];
  float acc1 = w1 * xfeat[(size_t)n*HDIM + ch1];
  float den0 = w0, den1 = w1;
  for (int p = beg; p < end; p++){
    int e = eid[p]; int s = srcA[e];
    float a0 = lrelu(al_s[(size_t)s*4 + h0] + ald0 + al_e[(size_t)e*4 + h0]);
    float a1 = lrelu(al_s[(size_t)s*4 + h1] + ald1 + al_e[(size_t)e*4 + h1]);
    float e0 = __expf(a0 - m0), e1 = __expf(a1 - m1);
    acc0 += e0 * xfeat[(size_t)s*HDIM + ch0];
    acc1 += e1 * xfeat[(size_t)s*HDIM + ch1];
    den0 += e0; den1 += e1;
  }
  float val = acc0/(den0 + 1e-16f) + acc1/(den1 + 1e-16f);
  __shared__ float sv[DD];
  if (hp == 0) sv[d] = val;
  __syncthreads();
  if (hp == 1) sv[d] += val;
  __syncthreads();
  if (t < DD) hOut[(size_t)n*DD + t] = fmaxf(sv[t]*0.25f + bias[t], 0.f);
}

// ---------------- edge head MLP ----------------
__global__ __launch_bounds__(256) void head_kernel(
    const float* __restrict__ p_src, const float* __restrict__ p_dst,
    const float* __restrict__ ea, const float* __restrict__ W1c,  // [32][128]
    const float* __restrict__ W2, const float* __restrict__ b2,
    const int* __restrict__ srcA, const int* __restrict__ dstA,
    float* __restrict__ out, int E){
  __shared__ float sW[EFEAT][DD];
  __shared__ float sW2[DD];
  int t = threadIdx.x;
  for (int i = t; i < EFEAT*DD; i += 256) sW[i >> 7][i & 127] = W1c[i];
  if (t < DD) sW2[t] = W2[t];
  __syncthreads();
  int wave = t >> 6, lane = t & 63;
  for (int q = 0; q < 4; q++){
    int e = blockIdx.x*16 + wave*4 + q;
    if (e >= E) break;
    int s = srcA[e], dd2 = dstA[e];
    int j0 = lane, j1 = lane + 64;
    float z0 = p_src[(size_t)s*DD + j0] + p_dst[(size_t)dd2*DD + j0];
    float z1 = p_src[(size_t)s*DD + j1] + p_dst[(size_t)dd2*DD + j1];
    #pragma unroll
    for (int f = 0; f < EFEAT; f++){
      float xv = ea[(size_t)e*EFEAT + f];
      z0 += xv*sW[f][j0]; z1 += xv*sW[f][j1];
    }
    z0 = fmaxf(z0, 0.f); z1 = fmaxf(z1, 0.f);
    float acc = waveReduceSum(z0*sW2[j0] + z1*sW2[j1]);
    if (lane == 0) out[e] = acc + b2[0];
  }
}

extern "C" void kernel_launch(void* const* d_in, const int* in_sizes, int n_in,
                              void* d_out, int out_size, void* d_ws, size_t ws_size,
                              hipStream_t stream){
  const float* x      = (const float*)d_in[0];
  const int*   eidx   = (const int*)d_in[1];
  const float* eattr  = (const float*)d_in[2];
  const float* gamma  = (const float*)d_in[3];
  const float* beta   = (const float*)d_in[4];
  const float* embW   = (const float*)d_in[5];
  const float* embB   = (const float*)d_in[6];
  const float* lnS    = (const float*)d_in[7];
  const float* lnB    = (const float*)d_in[8];
  const float* gatW   = (const float*)d_in[9];
  const float* attS   = (const float*)d_in[10];
  const float* attD   = (const float*)d_in[11];
  const float* gatWe  = (const float*)d_in[12];
  const float* attE   = (const float*)d_in[13];
  const float* gatB   = (const float*)d_in[14];
  const float* hW1    = (const float*)d_in[15];
  const float* hB1    = (const float*)d_in[16];
  const float* hW2    = (const float*)d_in[17];
  const float* hB2    = (const float*)d_in[18];
  float* out = (float*)d_out;

  int N = in_sizes[0] / DD;
  int E = in_sizes[1] / 2;
  int L = in_sizes[3] / DD;

  const int* srcA = eidx;
  const int* dstA = eidx + E;

  float* ws = (float*)d_ws;
  float* ea_sum  = ws + 0;       // 32
  float* we_att  = ws + 1024;    // L*32*4 = 768
  float* al_self = ws + 2048;    // L*4 = 24
  float* ws_att  = ws + 3072;    // L*128*8 = 6144
  int*   deg     = (int*)(ws + 16384);    // N
  int*   offs    = (int*)(ws + 49152);    // N+1
  int*   cursor  = (int*)(ws + 81920);    // N
  int*   eid     = (int*)(ws + 114688);   // E
  size_t o = 524288;
  float* h    = ws + o; o += (size_t)N*DD;
  float* hm   = ws + o; o += (size_t)N*DD;
  float* al_s = ws + o; o += (size_t)N*NHEAD;
  float* al_d = ws + o; o += (size_t)N*NHEAD;
  float* al_e = ws + o; o += (size_t)E*NHEAD;
  float* xfeat = ws + o; o += (size_t)N*HDIM;
  float* p_src = xfeat;               // reuse: head phase only
  float* p_dst = xfeat + (size_t)N*DD;

  hipMemsetAsync(ea_sum, 0, EFEAT*sizeof(float), stream);
  hipMemsetAsync(deg, 0, (size_t)N*sizeof(int), stream);
  ea_sum_kernel<<<256, 256, 0, stream>>>(eattr, ea_sum, E);
  hist_kernel<<<(E + 255)/256, 256, 0, stream>>>(dstA, deg, E);
  scan_kernel<<<1, 1024, 0, stream>>>(deg, offs, N);
  hipMemcpyAsync(cursor, offs, (size_t)N*sizeof(int), hipMemcpyDeviceToDevice, stream);
  scatter_kernel<<<(E + 255)/256, 256, 0, stream>>>(dstA, cursor, eid, E);
  fold_kernel<<<1, 256, 0, stream>>>(gatW, attS, attD, gatWe, attE, ea_sum,
                                     1.0f/(float)E, ws_att, we_att, al_self, L);
  linear_kernel<128><<<(N + 63)/64, 256, 0, stream>>>(x, embW, embB, h, N, 0);

  for (int l = 0; l < L; l++){
    ln_film_al_kernel<<<(N + 3)/4, 256, 0, stream>>>(h, lnS + l*DD, lnB + l*DD,
        gamma + l*DD, beta + l*DD, ws_att + (size_t)l*DD*8, hm, al_s, al_d, N);
    linear_kernel<512><<<(N + 31)/32, 256, 0, stream>>>(hm, gatW + (size_t)l*DD*HDIM,
        nullptr, xfeat, N, 0);
    al_edge_kernel<<<(E + 255)/256, 256, 0, stream>>>(eattr, we_att + (size_t)l*EFEAT*NHEAD,
        al_e, E);
    aggregate_kernel<<<N, 256, 0, stream>>>(xfeat, al_s, al_d, al_e,
        al_self + (size_t)l*NHEAD, offs, eid, srcA, gatB + l*DD, h, N);
  }

  linear_kernel<128><<<(N + 63)/64, 256, 0, stream>>>(h, hW1, hB1, p_src, N, 0);
  linear_kernel<128><<<(N + 63)/64, 256, 0, stream>>>(h, hW1 + DD*DD, nullptr, p_dst, N, 0);
  head_kernel<<<(E + 15)/16, 256, 0, stream>>>(p_src, p_dst, eattr, hW1 + 2*DD*DD,
      hW2, hB2, srcA, dstA, out, E);
}

// Round 2
// 2098.478 us; speedup vs baseline: 1.4887x; 1.4887x over previous
//
#include <hip/hip_runtime.h>

#define DD 128      // GNN_DIM == NODE_FEAT
#define HDIM 512    // H * D
#define EFEAT 32
#define NHEAD 4

__device__ __forceinline__ float lrelu(float x){ return x > 0.f ? x : 0.2f*x; }

__device__ __forceinline__ float waveReduceSum(float v){
  #pragma unroll
  for (int m = 1; m < 64; m <<= 1) v += __shfl_xor(v, m, 64);
  return v;
}
__device__ __forceinline__ float waveReduceMax(float v){
  #pragma unroll
  for (int m = 1; m < 64; m <<= 1) v = fmaxf(v, __shfl_xor(v, m, 64));
  return v;
}

// ---------------- edge-attr mean (sum, divided later) ----------------
__global__ void ea_sum_kernel(const float* __restrict__ ea, float* __restrict__ ea_sum, int E){
  __shared__ float s[EFEAT];
  int t = threadIdx.x;
  if (t < EFEAT) s[t] = 0.f;
  __syncthreads();
  int f = t & 31;
  int g = t >> 5;                 // 8 edge groups per block
  float acc = 0.f;
  for (int e = blockIdx.x*8 + g; e < E; e += gridDim.x*8)
    acc += ea[(size_t)e*EFEAT + f];
  atomicAdd(&s[f], acc);
  __syncthreads();
  if (t < EFEAT) atomicAdd(&ea_sum[t], s[t]);
}

// ---------------- CSR build over dst ----------------
__global__ void hist_kernel(const int* __restrict__ dst, int* __restrict__ deg, int E){
  int e = blockIdx.x*blockDim.x + threadIdx.x;
  if (e < E) atomicAdd(&deg[dst[e]], 1);
}

__global__ void scan_kernel(const int* __restrict__ deg, int* __restrict__ offs, int N){
  __shared__ int s[1024];
  __shared__ int carry;
  int t = threadIdx.x;
  if (t == 0) carry = 0;
  __syncthreads();
  for (int base = 0; base < N; base += 1024){
    int i = base + t;
    int v = (i < N) ? deg[i] : 0;
    s[t] = v;
    __syncthreads();
    for (int d = 1; d < 1024; d <<= 1){
      int x = (t >= d) ? s[t-d] : 0;
      __syncthreads();
      s[t] += x;
      __syncthreads();
    }
    int incl = s[t];
    int c = carry;
    if (i < N) offs[i] = c + incl - v;
    __syncthreads();
    if (t == 1023) carry = c + s[1023];
    __syncthreads();
  }
  if (t == 0) offs[N] = carry;
}

__global__ void scatter_kernel(const int* __restrict__ dst, const int* __restrict__ src,
                               int* __restrict__ cursor,
                               int* __restrict__ eid, int* __restrict__ srcp, int E){
  int e = blockIdx.x*blockDim.x + threadIdx.x;
  if (e < E){
    int p = atomicAdd(&cursor[dst[e]], 1);
    eid[p] = e;
    srcp[p] = src[e];
  }
}

// ---------------- fold attention vectors into W (all layers) ----------------
__global__ void fold_kernel(const float* __restrict__ gat_W, const float* __restrict__ att_src,
                            const float* __restrict__ att_dst, const float* __restrict__ gat_We,
                            const float* __restrict__ att_edge, const float* __restrict__ ea_sum,
                            float invE, float* __restrict__ ws_att, float* __restrict__ we_att,
                            float* __restrict__ al_self, int L){
  __shared__ float swe[6*EFEAT*NHEAD];
  int t = threadIdx.x;
  for (int idx = t; idx < L*DD*8; idx += 256){
    int j = idx & 7; int k = (idx >> 3) & 127; int l = idx >> 10;
    int h = j & 3;
    const float* att = (j < 4) ? att_src : att_dst;
    const float* Wl = gat_W + (size_t)l*DD*HDIM;
    const float* av = att + (size_t)(l*NHEAD + h)*DD;
    float acc = 0.f;
    for (int d = 0; d < DD; d++) acc += Wl[(size_t)k*HDIM + h*DD + d] * av[d];
    ws_att[idx] = acc;
  }
  for (int idx = t; idx < L*EFEAT*NHEAD; idx += 256){
    int h = idx & 3; int f = (idx >> 2) & 31; int l = idx >> 7;
    const float* Wel = gat_We + (size_t)l*EFEAT*HDIM;
    const float* av = att_edge + (size_t)(l*NHEAD + h)*DD;
    float acc = 0.f;
    for (int d = 0; d < DD; d++) acc += Wel[(size_t)f*HDIM + h*DD + d] * av[d];
    we_att[idx] = acc;
    swe[idx] = acc;
  }
  __syncthreads();
  for (int idx = t; idx < L*NHEAD; idx += 256){
    int h = idx & 3; int l = idx >> 2;
    float acc = 0.f;
    for (int f = 0; f < EFEAT; f++) acc += ea_sum[f]*invE * swe[(l*EFEAT + f)*NHEAD + h];
    al_self[idx] = acc;
  }
}

// ---------------- fp32 linear: C[M,128] = A[M,128] @ W[128,128] (+bias) ----------------
__global__ __launch_bounds__(256) void linear128_kernel(const float* __restrict__ A,
    const float* __restrict__ W, const float* __restrict__ bias,
    float* __restrict__ C, int M){
  constexpr int TM = 64;
  __shared__ float As[TM][DD];
  int t = threadIdx.x;
  int row0 = blockIdx.x*TM;
  for (int i = t; i < TM*DD; i += 256){
    int r = i >> 7, k = i & 127;
    int gr = row0 + r;
    As[r][k] = (gr < M) ? A[(size_t)gr*DD + k] : 0.f;
  }
  __syncthreads();
  int col = t & 127;
  int rbase = (t >> 7)*32;
  float acc0[32];
  #pragma unroll
  for (int r = 0; r < 32; r++) acc0[r] = 0.f;
  #pragma unroll 4
  for (int k = 0; k < DD; k++){
    float w0 = W[(size_t)k*DD + col];
    #pragma unroll
    for (int r = 0; r < 32; r++) acc0[r] += As[rbase + r][k]*w0;
  }
  float b0 = bias ? bias[col] : 0.f;
  for (int r = 0; r < 32; r++){
    int row = row0 + rbase + r;
    if (row < M) C[(size_t)row*DD + col] = acc0[r] + b0;
  }
}

// ---------------- post-aggregation linear: h[N,128] = relu(0.25 * z[N,512] @ Wbig + bias) ----
// Wbig[(h,k), d] = gat_W_l[k*512 + h*128 + d]
__global__ __launch_bounds__(256) void linear_post_kernel(const float* __restrict__ z,
    const float* __restrict__ W, const float* __restrict__ bias,
    float* __restrict__ hOut, int N){
  constexpr int TM = 16;
  __shared__ float Zs[TM][HDIM];   // 32 KB
  int t = threadIdx.x;
  int row0 = blockIdx.x*TM;
  for (int i = t*4; i < TM*HDIM; i += 1024){
    int r = i >> 9, k = i & 511;
    int gr = row0 + r;
    float4 v = make_float4(0.f,0.f,0.f,0.f);
    if (gr < N) v = *(const float4*)&z[(size_t)gr*HDIM + k];
    *(float4*)&Zs[r][k] = v;
  }
  __syncthreads();
  int col = t & 127;
  int rbase = (t >> 7)*8;
  float acc[8];
  #pragma unroll
  for (int r = 0; r < 8; r++) acc[r] = 0.f;
  #pragma unroll 4
  for (int kk = 0; kk < HDIM; kk++){
    int k = kk & 127, hh = kk >> 7;
    float wv = W[(size_t)k*HDIM + hh*DD + col];
    #pragma unroll
    for (int r = 0; r < 8; r++) acc[r] += Zs[rbase + r][kk]*wv;
  }
  float b0 = bias[col];
  for (int r = 0; r < 8; r++){
    int row = row0 + rbase + r;
    if (row < N) hOut[(size_t)row*DD + col] = fmaxf(acc[r]*0.25f + b0, 0.f);
  }
}

// ---------------- fused LayerNorm + FiLM + attention-logit projection ----------------
__global__ __launch_bounds__(256) void ln_film_al_kernel(const float* __restrict__ h,
    const float* __restrict__ ln_scale, const float* __restrict__ ln_bias,
    const float* __restrict__ gamma, const float* __restrict__ beta,
    const float* __restrict__ ws_att,   // [128][8] this layer
    float* __restrict__ hm, float* __restrict__ al_s, float* __restrict__ al_d, int N){
  __shared__ float s_att[DD*8];
  int t = threadIdx.x;
  for (int i = t; i < DD*8; i += 256) s_att[i] = ws_att[i];
  __syncthreads();
  int wave = t >> 6, lane = t & 63;
  int n = blockIdx.x*4 + wave;
  if (n >= N) return;
  int e0 = lane, e1 = lane + 64;
  float v0 = h[(size_t)n*DD + e0], v1 = h[(size_t)n*DD + e1];
  float sum = waveReduceSum(v0 + v1);
  float mu = sum * (1.f/128.f);
  float d0 = v0 - mu, d1 = v1 - mu;
  float vs = waveReduceSum(d0*d0 + d1*d1);
  float rstd = rsqrtf(vs*(1.f/128.f) + 1e-5f);
  float hn0 = d0*rstd*ln_scale[e0] + ln_bias[e0];
  float hn1 = d1*rstd*ln_scale[e1] + ln_bias[e1];
  float m0 = gamma[e0]*hn0 + beta[e0];
  float m1 = gamma[e1]*hn1 + beta[e1];
  hm[(size_t)n*DD + e0] = m0;
  hm[(size_t)n*DD + e1] = m1;
  #pragma unroll
  for (int j = 0; j < 8; j++){
    float a = m0*s_att[e0*8 + j] + m1*s_att[e1*8 + j];
    a = waveReduceSum(a);
    if (lane == 0){
      if (j < 4) al_s[n*4 + j] = a;
      else       al_d[n*4 + (j - 4)] = a;
    }
  }
}

// ---------------- per-edge attention logits for one layer ----------------
__global__ __launch_bounds__(256) void al_edge_kernel(const float* __restrict__ ea,
    const float* __restrict__ we_att,   // [32][4] this layer
    float* __restrict__ al_e, int E){
  __shared__ float sea[256][EFEAT + 1];
  __shared__ float swe[EFEAT*NHEAD];
  int t = threadIdx.x;
  if (t < EFEAT*NHEAD) swe[t] = we_att[t];
  int e0 = blockIdx.x*256;
  for (int i = t; i < 256*EFEAT; i += 256){
    int e = i >> 5, f = i & 31;
    sea[e][f] = (e0 + e < E) ? ea[(size_t)(e0 + e)*EFEAT + f] : 0.f;
  }
  __syncthreads();
  int e = e0 + t;
  if (e < E){
    float a0 = 0.f, a1 = 0.f, a2 = 0.f, a3 = 0.f;
    #pragma unroll
    for (int f = 0; f < EFEAT; f++){
      float x = sea[t][f];
      a0 += x*swe[f*4 + 0]; a1 += x*swe[f*4 + 1];
      a2 += x*swe[f*4 + 2]; a3 += x*swe[f*4 + 3];
    }
    al_e[(size_t)e*4 + 0] = a0; al_e[(size_t)e*4 + 1] = a1;
    al_e[(size_t)e*4 + 2] = a2; al_e[(size_t)e*4 + 3] = a3;
  }
}

// ---------------- per-edge softmax weights (wave per node) ----------------
__global__ __launch_bounds__(256) void edge_softmax_kernel(
    const float* __restrict__ al_s, const float* __restrict__ al_d,
    const float* __restrict__ al_e, const float* __restrict__ al_self4, // [4] this layer
    const int* __restrict__ offs, const int* __restrict__ srcp, const int* __restrict__ eid,
    float* __restrict__ w_csr, float* __restrict__ wself, float* __restrict__ den, int N){
  int wave = threadIdx.x >> 6, lane = threadIdx.x & 63;
  int n = blockIdx.x*4 + wave;
  if (n >= N) return;
  int beg = offs[n], end = offs[n + 1];
  float4 ald = *(const float4*)&al_d[(size_t)n*4];
  float4 alsn = *(const float4*)&al_s[(size_t)n*4];
  float4 aslf = *(const float4*)al_self4;
  float s0 = lrelu(alsn.x + ald.x + aslf.x);
  float s1 = lrelu(alsn.y + ald.y + aslf.y);
  float s2 = lrelu(alsn.z + ald.z + aslf.z);
  float s3 = lrelu(alsn.w + ald.w + aslf.w);
  float m0 = s0, m1 = s1, m2 = s2, m3 = s3;
  for (int p = beg + lane; p < end; p += 64){
    int s = srcp[p]; int e = eid[p];
    float4 as = *(const float4*)&al_s[(size_t)s*4];
    float4 ae = *(const float4*)&al_e[(size_t)e*4];
    m0 = fmaxf(m0, lrelu(as.x + ald.x + ae.x));
    m1 = fmaxf(m1, lrelu(as.y + ald.y + ae.y));
    m2 = fmaxf(m2, lrelu(as.z + ald.z + ae.z));
    m3 = fmaxf(m3, lrelu(as.w + ald.w + ae.w));
  }
  m0 = waveReduceMax(m0); m1 = waveReduceMax(m1);
  m2 = waveReduceMax(m2); m3 = waveReduceMax(m3);
  float e0 = __expf(s0 - m0), e1 = __expf(s1 - m1);
  float e2 = __expf(s2 - m2), e3 = __expf(s3 - m3);
  float a0 = 0.f, a1 = 0.f, a2 = 0.f, a3 = 0.f;
  for (int p = beg + lane; p < end; p += 64){
    int s = srcp[p]; int e = eid[p];
    float4 as = *(const float4*)&al_s[(size_t)s*4];
    float4 ae = *(const float4*)&al_e[(size_t)e*4];
    float w0 = __expf(lrelu(as.x + ald.x + ae.x) - m0);
    float w1 = __expf(lrelu(as.y + ald.y + ae.y) - m1);
    float w2 = __expf(lrelu(as.z + ald.z + ae.z) - m2);
    float w3 = __expf(lrelu(as.w + ald.w + ae.w) - m3);
    *(float4*)&w_csr[(size_t)p*4] = make_float4(w0, w1, w2, w3);
    a0 += w0; a1 += w1; a2 += w2; a3 += w3;
  }
  a0 = waveReduceSum(a0); a1 = waveReduceSum(a1);
  a2 = waveReduceSum(a2); a3 = waveReduceSum(a3);
  if (lane == 0){
    *(float4*)&wself[(size_t)n*4] = make_float4(e0, e1, e2, e3);
    *(float4*)&den[(size_t)n*4] = make_float4(e0 + a0, e1 + a1, e2 + a2, e3 + a3);
  }
}

// ---------------- aggregation in 128-dim input space: z[N,512] ----------------
__global__ __launch_bounds__(128) void aggregate2_kernel(
    const float* __restrict__ hm, const float* __restrict__ w_csr,
    const float* __restrict__ wself, const float* __restrict__ den,
    const int* __restrict__ offs, const int* __restrict__ srcp,
    float* __restrict__ z, int N){
  int n = blockIdx.x;
  int t = threadIdx.x;     // 0..127: input-space dim
  int beg = offs[n], end = offs[n + 1];
  float hv = hm[(size_t)n*DD + t];
  float4 wsf = *(const float4*)&wself[(size_t)n*4];
  float a0 = wsf.x*hv, a1 = wsf.y*hv, a2 = wsf.z*hv, a3 = wsf.w*hv;
  int s_next = (beg < end) ? srcp[beg] : 0;
  for (int p = beg; p < end; p++){
    int s = s_next;
    if (p + 1 < end) s_next = srcp[p + 1];
    float4 w4 = *(const float4*)&w_csr[(size_t)p*4];
    float v = hm[(size_t)s*DD + t];
    a0 += w4.x*v; a1 += w4.y*v; a2 += w4.z*v; a3 += w4.w*v;
  }
  float4 dn = *(const float4*)&den[(size_t)n*4];
  size_t zb = (size_t)n*HDIM;
  z[zb + 0*DD + t] = a0/(dn.x + 1e-16f);
  z[zb + 1*DD + t] = a1/(dn.y + 1e-16f);
  z[zb + 2*DD + t] = a2/(dn.z + 1e-16f);
  z[zb + 3*DD + t] = a3/(dn.w + 1e-16f);
}

// ---------------- edge head MLP ----------------
__global__ __launch_bounds__(256) void head_kernel(
    const float* __restrict__ p_src, const float* __restrict__ p_dst,
    const float* __restrict__ ea, const float* __restrict__ W1c,  // [32][128]
    const float* __restrict__ W2, const float* __restrict__ b2,
    const int* __restrict__ srcA, const int* __restrict__ dstA,
    float* __restrict__ out, int E){
  __shared__ float sW[EFEAT][DD];
  __shared__ float sW2[DD];
  int t = threadIdx.x;
  for (int i = t; i < EFEAT*DD; i += 256) sW[i >> 7][i & 127] = W1c[i];
  if (t < DD) sW2[t] = W2[t];
  __syncthreads();
  int wave = t >> 6, lane = t & 63;
  for (int q = 0; q < 4; q++){
    int e = blockIdx.x*16 + wave*4 + q;
    if (e >= E) break;
    int s = srcA[e], dd2 = dstA[e];
    int j0 = lane, j1 = lane + 64;
    float z0 = p_src[(size_t)s*DD + j0] + p_dst[(size_t)dd2*DD + j0];
    float z1 = p_src[(size_t)s*DD + j1] + p_dst[(size_t)dd2*DD + j1];
    #pragma unroll
    for (int f = 0; f < EFEAT; f++){
      float xv = ea[(size_t)e*EFEAT + f];
      z0 += xv*sW[f][j0]; z1 += xv*sW[f][j1];
    }
    z0 = fmaxf(z0, 0.f); z1 = fmaxf(z1, 0.f);
    float acc = waveReduceSum(z0*sW2[j0] + z1*sW2[j1]);
    if (lane == 0) out[e] = acc + b2[0];
  }
}

extern "C" void kernel_launch(void* const* d_in, const int* in_sizes, int n_in,
                              void* d_out, int out_size, void* d_ws, size_t ws_size,
                              hipStream_t stream){
  const float* x      = (const float*)d_in[0];
  const int*   eidx   = (const int*)d_in[1];
  const float* eattr  = (const float*)d_in[2];
  const float* gamma  = (const float*)d_in[3];
  const float* beta   = (const float*)d_in[4];
  const float* embW   = (const float*)d_in[5];
  const float* embB   = (const float*)d_in[6];
  const float* lnS    = (const float*)d_in[7];
  const float* lnB    = (const float*)d_in[8];
  const float* gatW   = (const float*)d_in[9];
  const float* attS   = (const float*)d_in[10];
  const float* attD   = (const float*)d_in[11];
  const float* gatWe  = (const float*)d_in[12];
  const float* attE   = (const float*)d_in[13];
  const float* gatB   = (const float*)d_in[14];
  const float* hW1    = (const float*)d_in[15];
  const float* hB1    = (const float*)d_in[16];
  const float* hW2    = (const float*)d_in[17];
  const float* hB2    = (const float*)d_in[18];
  float* out = (float*)d_out;

  int N = in_sizes[0] / DD;
  int E = in_sizes[1] / 2;
  int L = in_sizes[3] / DD;

  const int* srcA = eidx;
  const int* dstA = eidx + E;

  float* ws = (float*)d_ws;
  // small params
  float* ea_sum  = ws + 0;       // 32
  float* we_att  = ws + 64;      // L*32*4 = 768
  float* al_self = ws + 1024;    // L*4 = 24
  float* ws_att  = ws + 2048;    // L*128*8 = 6144 -> ends 8192
  size_t o = 8192;
  int* deg    = (int*)(ws + o); o += N;
  int* offs   = (int*)(ws + o); o += N + 1;
  int* cursor = (int*)(ws + o); o += N;
  int* eid    = (int*)(ws + o); o += E;
  int* srcp   = (int*)(ws + o); o += E;
  o = (o + 255) & ~(size_t)255;
  float* h     = ws + o; o += (size_t)N*DD;
  float* hm    = ws + o; o += (size_t)N*DD;
  float* al_s  = ws + o; o += (size_t)N*4;
  float* al_d  = ws + o; o += (size_t)N*4;
  float* al_e  = ws + o; o += (size_t)E*4;
  float* wbuf  = ws + o; o += (size_t)E*4;
  float* wself = ws + o; o += (size_t)N*4;
  float* den   = ws + o; o += (size_t)N*4;
  float* z     = ws + o; o += (size_t)N*HDIM;
  float* p_src = z;                     // head phase reuses z space
  float* p_dst = z + (size_t)N*DD;

  hipMemsetAsync(ea_sum, 0, EFEAT*sizeof(float), stream);
  hipMemsetAsync(deg, 0, (size_t)N*sizeof(int), stream);
  ea_sum_kernel<<<256, 256, 0, stream>>>(eattr, ea_sum, E);
  hist_kernel<<<(E + 255)/256, 256, 0, stream>>>(dstA, deg, E);
  scan_kernel<<<1, 1024, 0, stream>>>(deg, offs, N);
  hipMemcpyAsync(cursor, offs, (size_t)N*sizeof(int), hipMemcpyDeviceToDevice, stream);
  scatter_kernel<<<(E + 255)/256, 256, 0, stream>>>(dstA, srcA, cursor, eid, srcp, E);
  fold_kernel<<<1, 256, 0, stream>>>(gatW, attS, attD, gatWe, attE, ea_sum,
                                     1.0f/(float)E, ws_att, we_att, al_self, L);
  linear128_kernel<<<(N + 63)/64, 256, 0, stream>>>(x, embW, embB, h, N);

  for (int l = 0; l < L; l++){
    ln_film_al_kernel<<<(N + 3)/4, 256, 0, stream>>>(h, lnS + l*DD, lnB + l*DD,
        gamma + l*DD, beta + l*DD, ws_att + (size_t)l*DD*8, hm, al_s, al_d, N);
    al_edge_kernel<<<(E + 255)/256, 256, 0, stream>>>(eattr, we_att + (size_t)l*EFEAT*NHEAD,
        al_e, E);
    edge_softmax_kernel<<<(N + 3)/4, 256, 0, stream>>>(al_s, al_d, al_e,
        al_self + (size_t)l*NHEAD, offs, srcp, eid, wbuf, wself, den, N);
    aggregate2_kernel<<<N, 128, 0, stream>>>(hm, wbuf, wself, den, offs, srcp, z, N);
    linear_post_kernel<<<(N + 15)/16, 256, 0, stream>>>(z, gatW + (size_t)l*DD*HDIM,
        gatB + (size_t)l*DD, h, N);
  }

  linear128_kernel<<<(N + 63)/64, 256, 0, stream>>>(h, hW1, hB1, p_src, N);
  linear128_kernel<<<(N + 63)/64, 256, 0, stream>>>(h, hW1 + DD*DD, nullptr, p_dst, N);
  head_kernel<<<(E + 15)/16, 256, 0, stream>>>(p_src, p_dst, eattr, hW1 + 2*DD*DD,
      hW2, hB2, srcA, dstA, out, E);
}

// Round 3
// 1538.576 us; speedup vs baseline: 2.0305x; 1.3639x over previous
//
#include <hip/hip_runtime.h>

#define DD 128      // GNN_DIM == NODE_FEAT
#define HDIM 512    // H * D
#define EFEAT 32
#define NHEAD 4

typedef short s16x8 __attribute__((ext_vector_type(8)));
typedef float f32x4 __attribute__((ext_vector_type(4)));

__device__ __forceinline__ float lrelu(float x){ return x > 0.f ? x : 0.2f*x; }

__device__ __forceinline__ unsigned short f2bf(float f){
  unsigned u = __float_as_uint(f);
  unsigned r = (u + 0x7FFFu + ((u >> 16) & 1u)) >> 16;
  return (unsigned short)r;
}

__device__ __forceinline__ float waveReduceSum(float v){
  #pragma unroll
  for (int m = 1; m < 64; m <<= 1) v += __shfl_xor(v, m, 64);
  return v;
}
__device__ __forceinline__ float waveReduceMax(float v){
  #pragma unroll
  for (int m = 1; m < 64; m <<= 1) v = fmaxf(v, __shfl_xor(v, m, 64));
  return v;
}

// ---------------- edge-attr mean (sum, divided later) ----------------
__global__ void ea_sum_kernel(const float* __restrict__ ea, float* __restrict__ ea_sum, int E){
  __shared__ float s[EFEAT];
  int t = threadIdx.x;
  if (t < EFEAT) s[t] = 0.f;
  __syncthreads();
  int f = t & 31;
  int g = t >> 5;
  float acc = 0.f;
  for (int e = blockIdx.x*8 + g; e < E; e += gridDim.x*8)
    acc += ea[(size_t)e*EFEAT + f];
  atomicAdd(&s[f], acc);
  __syncthreads();
  if (t < EFEAT) atomicAdd(&ea_sum[t], s[t]);
}

// ---------------- CSR build over dst ----------------
__global__ void hist_kernel(const int* __restrict__ dst, int* __restrict__ deg, int E){
  int e = blockIdx.x*blockDim.x + threadIdx.x;
  if (e < E) atomicAdd(&deg[dst[e]], 1);
}

__global__ void scan_kernel(const int* __restrict__ deg, int* __restrict__ offs, int N){
  __shared__ int s[1024];
  int t = threadIdx.x;
  int chunk = (N + 1023) >> 10;
  int b = t*chunk, e = min(b + chunk, N);
  int sum = 0;
  for (int i = b; i < e; i++) sum += deg[i];
  s[t] = sum;
  __syncthreads();
  for (int d = 1; d < 1024; d <<= 1){
    int x = (t >= d) ? s[t - d] : 0;
    __syncthreads();
    s[t] += x;
    __syncthreads();
  }
  int run = s[t] - sum;   // exclusive prefix
  for (int i = b; i < e; i++){ offs[i] = run; run += deg[i]; }
  if (t == 1023) offs[N] = s[1023];
}

__global__ void scatter_kernel(const int* __restrict__ dst, const int* __restrict__ src,
                               int* __restrict__ cursor,
                               int* __restrict__ eid, int* __restrict__ srcp, int E){
  int e = blockIdx.x*blockDim.x + threadIdx.x;
  if (e < E){
    int p = atomicAdd(&cursor[dst[e]], 1);
    eid[p] = e;
    srcp[p] = src[e];
  }
}

// ---------------- parallel folds: wave per output ----------------
__global__ __launch_bounds__(256) void fold_ws_kernel(const float* __restrict__ gat_W,
    const float* __restrict__ att_src, const float* __restrict__ att_dst,
    float* __restrict__ ws_att, int L){
  int wave = threadIdx.x >> 6, lane = threadIdx.x & 63;
  int idx = blockIdx.x*4 + wave;
  if (idx >= L*DD*8) return;
  int j = idx & 7; int k = (idx >> 3) & 127; int l = idx >> 10;
  int h = j & 3;
  const float* att = (j < 4) ? att_src : att_dst;
  const float* av = att + (size_t)(l*NHEAD + h)*DD;
  const float* Wl = gat_W + (size_t)l*DD*HDIM + (size_t)k*HDIM + h*DD;
  float acc = Wl[lane]*av[lane] + Wl[lane + 64]*av[lane + 64];
  acc = waveReduceSum(acc);
  if (lane == 0) ws_att[idx] = acc;
}

__global__ __launch_bounds__(256) void fold_we_kernel(const float* __restrict__ gat_We,
    const float* __restrict__ att_edge, float* __restrict__ we_att, int L){
  int wave = threadIdx.x >> 6, lane = threadIdx.x & 63;
  int idx = blockIdx.x*4 + wave;
  if (idx >= L*EFEAT*NHEAD) return;
  int h = idx & 3; int f = (idx >> 2) & 31; int l = idx >> 7;
  const float* av = att_edge + (size_t)(l*NHEAD + h)*DD;
  const float* Wel = gat_We + (size_t)l*EFEAT*HDIM + (size_t)f*HDIM + h*DD;
  float acc = Wel[lane]*av[lane] + Wel[lane + 64]*av[lane + 64];
  acc = waveReduceSum(acc);
  if (lane == 0) we_att[idx] = acc;
}

__global__ void fold_self_kernel(const float* __restrict__ we_att,
    const float* __restrict__ ea_sum, float invE, float* __restrict__ al_self, int L){
  int t = threadIdx.x;
  if (t >= L*NHEAD) return;
  int h = t & 3; int l = t >> 2;
  float acc = 0.f;
  for (int f = 0; f < EFEAT; f++) acc += ea_sum[f]*invE * we_att[(l*EFEAT + f)*NHEAD + h];
  al_self[t] = acc;
}

// ---------------- transpose+convert gat_W to bf16 Bt[l][n=128][k=512] ----------------
// Bt[l][d][kk] = bf16(gat_W[l][(kk&127)*512 + (kk>>7)*128 + d])
__global__ void bt_prep_kernel(const float* __restrict__ gat_W,
                               unsigned short* __restrict__ Bt, int total){
  int i = blockIdx.x*blockDim.x + threadIdx.x;
  if (i >= total) return;
  int l = i >> 16; int rem = i & 65535;
  int d = rem >> 9; int kk = rem & 511;
  int k = kk & 127; int h = kk >> 7;
  Bt[i] = f2bf(gat_W[(size_t)l*DD*HDIM + (size_t)k*HDIM + h*DD + d]);
}

// ---------------- fp32 linear: C[M,128] = A[M,128] @ W[128,128] (+bias) ----------------
__global__ __launch_bounds__(256) void linear128_kernel(const float* __restrict__ A,
    const float* __restrict__ W, const float* __restrict__ bias,
    float* __restrict__ C, int M){
  constexpr int TM = 64;
  __shared__ float As[TM][DD];
  int t = threadIdx.x;
  int row0 = blockIdx.x*TM;
  for (int i = t; i < TM*DD; i += 256){
    int r = i >> 7, k = i & 127;
    int gr = row0 + r;
    As[r][k] = (gr < M) ? A[(size_t)gr*DD + k] : 0.f;
  }
  __syncthreads();
  int col = t & 127;
  int rbase = (t >> 7)*32;
  float acc0[32];
  #pragma unroll
  for (int r = 0; r < 32; r++) acc0[r] = 0.f;
  #pragma unroll 4
  for (int k = 0; k < DD; k++){
    float w0 = W[(size_t)k*DD + col];
    #pragma unroll
    for (int r = 0; r < 32; r++) acc0[r] += As[rbase + r][k]*w0;
  }
  float b0 = bias ? bias[col] : 0.f;
  for (int r = 0; r < 32; r++){
    int row = row0 + rbase + r;
    if (row < M) C[(size_t)row*DD + col] = acc0[r] + b0;
  }
}

// ---------------- MFMA bf16 GEMM: h[N,128] = relu(0.25 * z[N,512] @ B + bias) ----------
// z: bf16 [Npad,512]; Bt: bf16 [128][512] (pre-transposed: Bt[n][k] = B[k][n])
// A-frag: A[m=lane&15][k=quad*8+j]; B-frag: B[k=quad*8+j][n=lane&15];
// C/D: col=lane&15, row=quad*4+reg   [per verified gfx950 layouts]
__global__ __launch_bounds__(256) void gemm_post_kernel(
    const unsigned short* __restrict__ z, const unsigned short* __restrict__ Bt,
    const float* __restrict__ bias, float* __restrict__ hOut, int N){
  int t = threadIdx.x;
  int wave = t >> 6, lane = t & 63;
  int ln15 = lane & 15, quad = lane >> 4;
  int row0 = blockIdx.x*64 + wave*16;
  int arow = row0 + ln15;
  if (arow > N - 1) arow = N - 1;          // clamp (pad rows unused)
  const unsigned short* aptr = z + (size_t)arow*HDIM + quad*8;
  const unsigned short* bptr = Bt + (size_t)ln15*HDIM + quad*8;

  f32x4 acc[8];
  #pragma unroll
  for (int c = 0; c < 8; c++) acc[c] = (f32x4)(0.f);

  #pragma unroll 4
  for (int ks = 0; ks < 16; ks++){
    s16x8 a = *(const s16x8*)(aptr + ks*32);
    #pragma unroll
    for (int c = 0; c < 8; c++){
      s16x8 b = *(const s16x8*)(bptr + (size_t)c*16*HDIM + ks*32);
      acc[c] = __builtin_amdgcn_mfma_f32_16x16x32_bf16(a, b, acc[c], 0, 0, 0);
    }
  }

  #pragma unroll
  for (int c = 0; c < 8; c++){
    int col = c*16 + ln15;
    float b0 = bias[col];
    #pragma unroll
    for (int r = 0; r < 4; r++){
      int row = row0 + quad*4 + r;
      if (row < N)
        hOut[(size_t)row*DD + col] = fmaxf(0.25f*acc[c][r] + b0, 0.f);
    }
  }
}

// ---------------- fused LayerNorm + FiLM + attention-logit projection ----------------
__global__ __launch_bounds__(256) void ln_film_al_kernel(const float* __restrict__ h,
    const float* __restrict__ ln_scale, const float* __restrict__ ln_bias,
    const float* __restrict__ gamma, const float* __restrict__ beta,
    const float* __restrict__ ws_att,   // [128][8] this layer
    float* __restrict__ hm, float* __restrict__ al_s, float* __restrict__ al_d, int N){
  __shared__ float s_att[DD*8];
  int t = threadIdx.x;
  for (int i = t; i < DD*8; i += 256) s_att[i] = ws_att[i];
  __syncthreads();
  int wave = t >> 6, lane = t & 63;
  int n = blockIdx.x*4 + wave;
  if (n >= N) return;
  int e0 = lane, e1 = lane + 64;
  float v0 = h[(size_t)n*DD + e0], v1 = h[(size_t)n*DD + e1];
  float sum = waveReduceSum(v0 + v1);
  float mu = sum * (1.f/128.f);
  float d0 = v0 - mu, d1 = v1 - mu;
  float vs = waveReduceSum(d0*d0 + d1*d1);
  float rstd = rsqrtf(vs*(1.f/128.f) + 1e-5f);
  float hn0 = d0*rstd*ln_scale[e0] + ln_bias[e0];
  float hn1 = d1*rstd*ln_scale[e1] + ln_bias[e1];
  float m0 = gamma[e0]*hn0 + beta[e0];
  float m1 = gamma[e1]*hn1 + beta[e1];
  hm[(size_t)n*DD + e0] = m0;
  hm[(size_t)n*DD + e1] = m1;
  #pragma unroll
  for (int j = 0; j < 8; j++){
    float a = m0*s_att[e0*8 + j] + m1*s_att[e1*8 + j];
    a = waveReduceSum(a);
    if (lane == 0){
      if (j < 4) al_s[n*4 + j] = a;
      else       al_d[n*4 + (j - 4)] = a;
    }
  }
}

// ---------------- per-edge attention logits for one layer ----------------
__global__ __launch_bounds__(256) void al_edge_kernel(const float* __restrict__ ea,
    const float* __restrict__ we_att,   // [32][4] this layer
    float* __restrict__ al_e, int E){
  __shared__ float sea[256][EFEAT + 1];
  __shared__ float swe[EFEAT*NHEAD];
  int t = threadIdx.x;
  if (t < EFEAT*NHEAD) swe[t] = we_att[t];
  int e0 = blockIdx.x*256;
  for (int i = t; i < 256*EFEAT; i += 256){
    int e = i >> 5, f = i & 31;
    sea[e][f] = (e0 + e < E) ? ea[(size_t)(e0 + e)*EFEAT + f] : 0.f;
  }
  __syncthreads();
  int e = e0 + t;
  if (e < E){
    float a0 = 0.f, a1 = 0.f, a2 = 0.f, a3 = 0.f;
    #pragma unroll
    for (int f = 0; f < EFEAT; f++){
      float x = sea[t][f];
      a0 += x*swe[f*4 + 0]; a1 += x*swe[f*4 + 1];
      a2 += x*swe[f*4 + 2]; a3 += x*swe[f*4 + 3];
    }
    al_e[(size_t)e*4 + 0] = a0; al_e[(size_t)e*4 + 1] = a1;
    al_e[(size_t)e*4 + 2] = a2; al_e[(size_t)e*4 + 3] = a3;
  }
}

// ---------------- per-edge softmax weights (wave per node) ----------------
__global__ __launch_bounds__(256) void edge_softmax_kernel(
    const float* __restrict__ al_s, const float* __restrict__ al_d,
    const float* __restrict__ al_e, const float* __restrict__ al_self4,
    const int* __restrict__ offs, const int* __restrict__ srcp, const int* __restrict__ eid,
    float* __restrict__ w_csr, float* __restrict__ wself, float* __restrict__ den, int N){
  int wave = threadIdx.x >> 6, lane = threadIdx.x & 63;
  int n = blockIdx.x*4 + wave;
  if (n >= N) return;
  int beg = offs[n], end = offs[n + 1];
  float4 ald = *(const float4*)&al_d[(size_t)n*4];
  float4 alsn = *(const float4*)&al_s[(size_t)n*4];
  float4 aslf = *(const float4*)al_self4;
  float s0 = lrelu(alsn.x + ald.x + aslf.x);
  float s1 = lrelu(alsn.y + ald.y + aslf.y);
  float s2 = lrelu(alsn.z + ald.z + aslf.z);
  float s3 = lrelu(alsn.w + ald.w + aslf.w);
  float m0 = s0, m1 = s1, m2 = s2, m3 = s3;
  for (int p = beg + lane; p < end; p += 64){
    int s = srcp[p]; int e = eid[p];
    float4 as = *(const float4*)&al_s[(size_t)s*4];
    float4 ae = *(const float4*)&al_e[(size_t)e*4];
    m0 = fmaxf(m0, lrelu(as.x + ald.x + ae.x));
    m1 = fmaxf(m1, lrelu(as.y + ald.y + ae.y));
    m2 = fmaxf(m2, lrelu(as.z + ald.z + ae.z));
    m3 = fmaxf(m3, lrelu(as.w + ald.w + ae.w));
  }
  m0 = waveReduceMax(m0); m1 = waveReduceMax(m1);
  m2 = waveReduceMax(m2); m3 = waveReduceMax(m3);
  float e0 = __expf(s0 - m0), e1 = __expf(s1 - m1);
  float e2 = __expf(s2 - m2), e3 = __expf(s3 - m3);
  float a0 = 0.f, a1 = 0.f, a2 = 0.f, a3 = 0.f;
  for (int p = beg + lane; p < end; p += 64){
    int s = srcp[p]; int e = eid[p];
    float4 as = *(const float4*)&al_s[(size_t)s*4];
    float4 ae = *(const float4*)&al_e[(size_t)e*4];
    float w0 = __expf(lrelu(as.x + ald.x + ae.x) - m0);
    float w1 = __expf(lrelu(as.y + ald.y + ae.y) - m1);
    float w2 = __expf(lrelu(as.z + ald.z + ae.z) - m2);
    float w3 = __expf(lrelu(as.w + ald.w + ae.w) - m3);
    *(float4*)&w_csr[(size_t)p*4] = make_float4(w0, w1, w2, w3);
    a0 += w0; a1 += w1; a2 += w2; a3 += w3;
  }
  a0 = waveReduceSum(a0); a1 = waveReduceSum(a1);
  a2 = waveReduceSum(a2); a3 = waveReduceSum(a3);
  if (lane == 0){
    *(float4*)&wself[(size_t)n*4] = make_float4(e0, e1, e2, e3);
    *(float4*)&den[(size_t)n*4] = make_float4(e0 + a0, e1 + a1, e2 + a2, e3 + a3);
  }
}

// ---------------- aggregation in 128-dim input space: z[N,512] (bf16 out) ----------------
__global__ __launch_bounds__(128) void aggregate2_kernel(
    const float* __restrict__ hm, const float* __restrict__ w_csr,
    const float* __restrict__ wself, const float* __restrict__ den,
    const int* __restrict__ offs, const int* __restrict__ srcp,
    unsigned short* __restrict__ z, int N){
  int n = blockIdx.x;
  int t = threadIdx.x;
  int beg = offs[n], end = offs[n + 1];
  float hv = hm[(size_t)n*DD + t];
  float4 wsf = *(const float4*)&wself[(size_t)n*4];
  float a0 = wsf.x*hv, a1 = wsf.y*hv, a2 = wsf.z*hv, a3 = wsf.w*hv;
  int s_next = (beg < end) ? srcp[beg] : 0;
  for (int p = beg; p < end; p++){
    int s = s_next;
    if (p + 1 < end) s_next = srcp[p + 1];
    float4 w4 = *(const float4*)&w_csr[(size_t)p*4];
    float v = hm[(size_t)s*DD + t];
    a0 += w4.x*v; a1 += w4.y*v; a2 += w4.z*v; a3 += w4.w*v;
  }
  float4 dn = *(const float4*)&den[(size_t)n*4];
  size_t zb = (size_t)n*HDIM;
  z[zb + 0*DD + t] = f2bf(a0/(dn.x + 1e-16f));
  z[zb + 1*DD + t] = f2bf(a1/(dn.y + 1e-16f));
  z[zb + 2*DD + t] = f2bf(a2/(dn.z + 1e-16f));
  z[zb + 3*DD + t] = f2bf(a3/(dn.w + 1e-16f));
}

// ---------------- edge head MLP ----------------
__global__ __launch_bounds__(256) void head_kernel(
    const float* __restrict__ p_src, const float* __restrict__ p_dst,
    const float* __restrict__ ea, const float* __restrict__ W1c,
    const float* __restrict__ W2, const float* __restrict__ b2,
    const int* __restrict__ srcA, const int* __restrict__ dstA,
    float* __restrict__ out, int E){
  __shared__ float sW[EFEAT][DD];
  __shared__ float sW2[DD];
  int t = threadIdx.x;
  for (int i = t; i < EFEAT*DD; i += 256) sW[i >> 7][i & 127] = W1c[i];
  if (t < DD) sW2[t] = W2[t];
  __syncthreads();
  int wave = t >> 6, lane = t & 63;
  for (int q = 0; q < 4; q++){
    int e = blockIdx.x*16 + wave*4 + q;
    if (e >= E) break;
    int s = srcA[e], dd2 = dstA[e];
    int j0 = lane, j1 = lane + 64;
    float z0 = p_src[(size_t)s*DD + j0] + p_dst[(size_t)dd2*DD + j0];
    float z1 = p_src[(size_t)s*DD + j1] + p_dst[(size_t)dd2*DD + j1];
    #pragma unroll
    for (int f = 0; f < EFEAT; f++){
      float xv = ea[(size_t)e*EFEAT + f];
      z0 += xv*sW[f][j0]; z1 += xv*sW[f][j1];
    }
    z0 = fmaxf(z0, 0.f); z1 = fmaxf(z1, 0.f);
    float acc = waveReduceSum(z0*sW2[j0] + z1*sW2[j1]);
    if (lane == 0) out[e] = acc + b2[0];
  }
}

extern "C" void kernel_launch(void* const* d_in, const int* in_sizes, int n_in,
                              void* d_out, int out_size, void* d_ws, size_t ws_size,
                              hipStream_t stream){
  const float* x      = (const float*)d_in[0];
  const int*   eidx   = (const int*)d_in[1];
  const float* eattr  = (const float*)d_in[2];
  const float* gamma  = (const float*)d_in[3];
  const float* beta   = (const float*)d_in[4];
  const float* embW   = (const float*)d_in[5];
  const float* embB   = (const float*)d_in[6];
  const float* lnS    = (const float*)d_in[7];
  const float* lnB    = (const float*)d_in[8];
  const float* gatW   = (const float*)d_in[9];
  const float* attS   = (const float*)d_in[10];
  const float* attD   = (const float*)d_in[11];
  const float* gatWe  = (const float*)d_in[12];
  const float* attE   = (const float*)d_in[13];
  const float* gatB   = (const float*)d_in[14];
  const float* hW1    = (const float*)d_in[15];
  const float* hB1    = (const float*)d_in[16];
  const float* hW2    = (const float*)d_in[17];
  const float* hB2    = (const float*)d_in[18];
  float* out = (float*)d_out;

  int N = in_sizes[0] / DD;
  int E = in_sizes[1] / 2;
  int L = in_sizes[3] / DD;
  int Npad = (N + 63) & ~63;

  const int* srcA = eidx;
  const int* dstA = eidx + E;

  float* ws = (float*)d_ws;
  float* ea_sum  = ws + 0;
  float* we_att  = ws + 64;      // L*128
  float* al_self = ws + 1024;    // L*4
  float* ws_att  = ws + 2048;    // L*1024 -> ends 8192
  size_t o = 8192;
  int* deg    = (int*)(ws + o); o += N;
  int* offs   = (int*)(ws + o); o += N + 1;
  int* cursor = (int*)(ws + o); o += N;
  int* eid    = (int*)(ws + o); o += E;
  int* srcp   = (int*)(ws + o); o += E;
  o = (o + 255) & ~(size_t)255;
  unsigned short* Bt = (unsigned short*)(ws + o); o += (size_t)L*DD*HDIM/2;  // bf16
  float* h     = ws + o; o += (size_t)N*DD;
  float* hm    = ws + o; o += (size_t)N*DD;
  float* al_s  = ws + o; o += (size_t)N*4;
  float* al_d  = ws + o; o += (size_t)N*4;
  float* al_e  = ws + o; o += (size_t)E*4;
  float* wbuf  = ws + o; o += (size_t)E*4;
  float* wself = ws + o; o += (size_t)N*4;
  float* den   = ws + o; o += (size_t)N*4;
  unsigned short* z = (unsigned short*)(ws + o); o += (size_t)Npad*HDIM/2;   // bf16
  // head phase reuses loop buffers (hm and z are dead by then)
  float* p_src = hm;
  float* p_dst = (float*)z;

  hipMemsetAsync(ea_sum, 0, EFEAT*sizeof(float), stream);
  hipMemsetAsync(deg, 0, (size_t)N*sizeof(int), stream);
  ea_sum_kernel<<<256, 256, 0, stream>>>(eattr, ea_sum, E);
  hist_kernel<<<(E + 255)/256, 256, 0, stream>>>(dstA, deg, E);
  scan_kernel<<<1, 1024, 0, stream>>>(deg, offs, N);
  hipMemcpyAsync(cursor, offs, (size_t)N*sizeof(int), hipMemcpyDeviceToDevice, stream);
  scatter_kernel<<<(E + 255)/256, 256, 0, stream>>>(dstA, srcA, cursor, eid, srcp, E);
  fold_ws_kernel<<<(L*DD*8 + 3)/4, 256, 0, stream>>>(gatW, attS, attD, ws_att, L);
  fold_we_kernel<<<(L*EFEAT*NHEAD + 3)/4, 256, 0, stream>>>(gatWe, attE, we_att, L);
  fold_self_kernel<<<1, 64, 0, stream>>>(we_att, ea_sum, 1.0f/(float)E, al_self, L);
  bt_prep_kernel<<<(L*DD*HDIM + 255)/256, 256, 0, stream>>>(gatW, Bt, L*DD*HDIM);
  linear128_kernel<<<(N + 63)/64, 256, 0, stream>>>(x, embW, embB, h, N);

  for (int l = 0; l < L; l++){
    ln_film_al_kernel<<<(N + 3)/4, 256, 0, stream>>>(h, lnS + l*DD, lnB + l*DD,
        gamma + l*DD, beta + l*DD, ws_att + (size_t)l*DD*8, hm, al_s, al_d, N);
    al_edge_kernel<<<(E + 255)/256, 256, 0, stream>>>(eattr, we_att + (size_t)l*EFEAT*NHEAD,
        al_e, E);
    edge_softmax_kernel<<<(N + 3)/4, 256, 0, stream>>>(al_s, al_d, al_e,
        al_self + (size_t)l*NHEAD, offs, srcp, eid, wbuf, wself, den, N);
    aggregate2_kernel<<<N, 128, 0, stream>>>(hm, wbuf, wself, den, offs, srcp, z, N);
    gemm_post_kernel<<<(N + 63)/64, 256, 0, stream>>>(z, Bt + (size_t)l*DD*HDIM,
        gatB + (size_t)l*DD, h, N);
  }

  linear128_kernel<<<(N + 63)/64, 256, 0, stream>>>(h, hW1, hB1, p_src, N);
  linear128_kernel<<<(N + 63)/64, 256, 0, stream>>>(h, hW1 + DD*DD, nullptr, p_dst, N);
  head_kernel<<<(E + 15)/16, 256, 0, stream>>>(p_src, p_dst, eattr, hW1 + 2*DD*DD,
      hW2, hB2, srcA, dstA, out, E);
}

// Round 4
// 1333.305 us; speedup vs baseline: 2.3431x; 1.1540x over previous
//
#include <hip/hip_runtime.h>

#define DD 128      // GNN_DIM == NODE_FEAT
#define HDIM 512    // H * D
#define EFEAT 32
#define NHEAD 4

typedef short s16x8 __attribute__((ext_vector_type(8)));
typedef float f32x4 __attribute__((ext_vector_type(4)));

__device__ __forceinline__ float lrelu(float x){ return x > 0.f ? x : 0.2f*x; }

__device__ __forceinline__ unsigned short f2bf(float f){
  unsigned u = __float_as_uint(f);
  unsigned r = (u + 0x7FFFu + ((u >> 16) & 1u)) >> 16;
  return (unsigned short)r;
}
__device__ __forceinline__ float bf2f(unsigned short u){
  return __uint_as_float(((unsigned)u) << 16);
}

__device__ __forceinline__ float waveReduceSum(float v){
  #pragma unroll
  for (int m = 1; m < 64; m <<= 1) v += __shfl_xor(v, m, 64);
  return v;
}

// ---------------- edge-attr mean (sum, divided later) ----------------
__global__ void ea_sum_kernel(const float* __restrict__ ea, float* __restrict__ ea_sum, int E){
  __shared__ float s[EFEAT];
  int t = threadIdx.x;
  if (t < EFEAT) s[t] = 0.f;
  __syncthreads();
  int f = t & 31;
  int g = t >> 5;
  float acc = 0.f;
  for (int e = blockIdx.x*8 + g; e < E; e += gridDim.x*8)
    acc += ea[(size_t)e*EFEAT + f];
  atomicAdd(&s[f], acc);
  __syncthreads();
  if (t < EFEAT) atomicAdd(&ea_sum[t], s[t]);
}

// ---------------- CSR build over dst ----------------
__global__ void hist_kernel(const int* __restrict__ dst, int* __restrict__ deg, int E){
  int e = blockIdx.x*blockDim.x + threadIdx.x;
  if (e < E) atomicAdd(&deg[dst[e]], 1);
}

__global__ void scan_kernel(const int* __restrict__ deg, int* __restrict__ offs, int N){
  __shared__ int s[1024];
  int t = threadIdx.x;
  int chunk = (N + 1023) >> 10;
  int b = t*chunk, e = min(b + chunk, N);
  int sum = 0;
  for (int i = b; i < e; i++) sum += deg[i];
  s[t] = sum;
  __syncthreads();
  for (int d = 1; d < 1024; d <<= 1){
    int x = (t >= d) ? s[t - d] : 0;
    __syncthreads();
    s[t] += x;
    __syncthreads();
  }
  int run = s[t] - sum;   // exclusive prefix
  for (int i = b; i < e; i++){ offs[i] = run; run += deg[i]; }
  if (t == 1023) offs[N] = s[1023];
}

__global__ void scatter_kernel(const int* __restrict__ dst, const int* __restrict__ src,
                               int* __restrict__ cursor, int* __restrict__ eid,
                               int* __restrict__ srcp, int* __restrict__ dstp, int E){
  int e = blockIdx.x*blockDim.x + threadIdx.x;
  if (e < E){
    int d = dst[e];
    int p = atomicAdd(&cursor[d], 1);
    eid[p] = e;
    srcp[p] = src[e];
    dstp[p] = d;
  }
}

// ---------------- permute+convert edge attrs into CSR order (bf16) ----------------
__global__ void eap_prep_kernel(const float* __restrict__ ea, const int* __restrict__ eid,
                                unsigned short* __restrict__ eap, int total){
  int idx = blockIdx.x*blockDim.x + threadIdx.x;
  if (idx >= total) return;
  int p = idx >> 5, f = idx & 31;
  eap[idx] = f2bf(ea[(size_t)eid[p]*EFEAT + f]);
}

// ---------------- parallel folds: wave per output ----------------
__global__ __launch_bounds__(256) void fold_ws_kernel(const float* __restrict__ gat_W,
    const float* __restrict__ att_src, const float* __restrict__ att_dst,
    float* __restrict__ ws_att, int L){
  int wave = threadIdx.x >> 6, lane = threadIdx.x & 63;
  int idx = blockIdx.x*4 + wave;
  if (idx >= L*DD*8) return;
  int j = idx & 7; int k = (idx >> 3) & 127; int l = idx >> 10;
  int h = j & 3;
  const float* att = (j < 4) ? att_src : att_dst;
  const float* av = att + (size_t)(l*NHEAD + h)*DD;
  const float* Wl = gat_W + (size_t)l*DD*HDIM + (size_t)k*HDIM + h*DD;
  float acc = Wl[lane]*av[lane] + Wl[lane + 64]*av[lane + 64];
  acc = waveReduceSum(acc);
  if (lane == 0) ws_att[idx] = acc;
}

__global__ __launch_bounds__(256) void fold_we_kernel(const float* __restrict__ gat_We,
    const float* __restrict__ att_edge, float* __restrict__ we_att, int L){
  int wave = threadIdx.x >> 6, lane = threadIdx.x & 63;
  int idx = blockIdx.x*4 + wave;
  if (idx >= L*EFEAT*NHEAD) return;
  int h = idx & 3; int f = (idx >> 2) & 31; int l = idx >> 7;
  const float* av = att_edge + (size_t)(l*NHEAD + h)*DD;
  const float* Wel = gat_We + (size_t)l*EFEAT*HDIM + (size_t)f*HDIM + h*DD;
  float acc = Wel[lane]*av[lane] + Wel[lane + 64]*av[lane + 64];
  acc = waveReduceSum(acc);
  if (lane == 0) we_att[idx] = acc;
}

__global__ void fold_self_kernel(const float* __restrict__ we_att,
    const float* __restrict__ ea_sum, float invE, float* __restrict__ al_self, int L){
  int t = threadIdx.x;
  if (t >= L*NHEAD) return;
  int h = t & 3; int l = t >> 2;
  float acc = 0.f;
  for (int f = 0; f < EFEAT; f++) acc += ea_sum[f]*invE * we_att[(l*EFEAT + f)*NHEAD + h];
  al_self[t] = acc;
}

// ---------------- transpose+convert gat_W to bf16 Bt[l][n=128][k=512] ----------------
__global__ void bt_prep_kernel(const float* __restrict__ gat_W,
                               unsigned short* __restrict__ Bt, int total){
  int i = blockIdx.x*blockDim.x + threadIdx.x;
  if (i >= total) return;
  int l = i >> 16; int rem = i & 65535;
  int d = rem >> 9; int kk = rem & 511;
  int k = kk & 127; int h = kk >> 7;
  Bt[i] = f2bf(gat_W[(size_t)l*DD*HDIM + (size_t)k*HDIM + h*DD + d]);
}

// ---------------- fp32 linear: C[M,128] = A[M,128] @ W[128,128] (+bias) ----------------
__global__ __launch_bounds__(256) void linear128_kernel(const float* __restrict__ A,
    const float* __restrict__ W, const float* __restrict__ bias,
    float* __restrict__ C, int M){
  constexpr int TM = 64;
  __shared__ float As[TM][DD];
  int t = threadIdx.x;
  int row0 = blockIdx.x*TM;
  for (int i = t; i < TM*DD; i += 256){
    int r = i >> 7, k = i & 127;
    int gr = row0 + r;
    As[r][k] = (gr < M) ? A[(size_t)gr*DD + k] : 0.f;
  }
  __syncthreads();
  int col = t & 127;
  int rbase = (t >> 7)*32;
  float acc0[32];
  #pragma unroll
  for (int r = 0; r < 32; r++) acc0[r] = 0.f;
  #pragma unroll 4
  for (int k = 0; k < DD; k++){
    float w0 = W[(size_t)k*DD + col];
    #pragma unroll
    for (int r = 0; r < 32; r++) acc0[r] += As[rbase + r][k]*w0;
  }
  float b0 = bias ? bias[col] : 0.f;
  for (int r = 0; r < 32; r++){
    int row = row0 + rbase + r;
    if (row < M) C[(size_t)row*DD + col] = acc0[r] + b0;
  }
}

// same, bf16 output
__global__ __launch_bounds__(256) void linear128_bf16_kernel(const float* __restrict__ A,
    const float* __restrict__ W, const float* __restrict__ bias,
    unsigned short* __restrict__ C, int M){
  constexpr int TM = 64;
  __shared__ float As[TM][DD];
  int t = threadIdx.x;
  int row0 = blockIdx.x*TM;
  for (int i = t; i < TM*DD; i += 256){
    int r = i >> 7, k = i & 127;
    int gr = row0 + r;
    As[r][k] = (gr < M) ? A[(size_t)gr*DD + k] : 0.f;
  }
  __syncthreads();
  int col = t & 127;
  int rbase = (t >> 7)*32;
  float acc0[32];
  #pragma unroll
  for (int r = 0; r < 32; r++) acc0[r] = 0.f;
  #pragma unroll 4
  for (int k = 0; k < DD; k++){
    float w0 = W[(size_t)k*DD + col];
    #pragma unroll
    for (int r = 0; r < 32; r++) acc0[r] += As[rbase + r][k]*w0;
  }
  float b0 = bias ? bias[col] : 0.f;
  for (int r = 0; r < 32; r++){
    int row = row0 + rbase + r;
    if (row < M) C[(size_t)row*DD + col] = f2bf(acc0[r] + b0);
  }
}

// ---------------- MFMA bf16 GEMM: h[N,128] = relu(0.25 * z[N,512] @ B + bias) ----------
__global__ __launch_bounds__(256) void gemm_post_kernel(
    const unsigned short* __restrict__ z, const unsigned short* __restrict__ Bt,
    const float* __restrict__ bias, float* __restrict__ hOut, int N){
  int t = threadIdx.x;
  int wave = t >> 6, lane = t & 63;
  int ln15 = lane & 15, quad = lane >> 4;
  int row0 = blockIdx.x*64 + wave*16;
  int arow = row0 + ln15;
  if (arow > N - 1) arow = N - 1;
  const unsigned short* aptr = z + (size_t)arow*HDIM + quad*8;
  const unsigned short* bptr = Bt + (size_t)ln15*HDIM + quad*8;

  f32x4 acc[8];
  #pragma unroll
  for (int c = 0; c < 8; c++) acc[c] = (f32x4)(0.f);

  #pragma unroll 4
  for (int ks = 0; ks < 16; ks++){
    s16x8 a = *(const s16x8*)(aptr + ks*32);
    #pragma unroll
    for (int c = 0; c < 8; c++){
      s16x8 b = *(const s16x8*)(bptr + (size_t)c*16*HDIM + ks*32);
      acc[c] = __builtin_amdgcn_mfma_f32_16x16x32_bf16(a, b, acc[c], 0, 0, 0);
    }
  }

  #pragma unroll
  for (int c = 0; c < 8; c++){
    int col = c*16 + ln15;
    float b0 = bias[col];
    #pragma unroll
    for (int r = 0; r < 4; r++){
      int row = row0 + quad*4 + r;
      if (row < N)
        hOut[(size_t)row*DD + col] = fmaxf(0.25f*acc[c][r] + b0, 0.f);
    }
  }
}

// ---------------- fused LayerNorm + FiLM + attention-logit projection ----------------
// hm stored bf16
__global__ __launch_bounds__(256) void ln_film_al_kernel(const float* __restrict__ h,
    const float* __restrict__ ln_scale, const float* __restrict__ ln_bias,
    const float* __restrict__ gamma, const float* __restrict__ beta,
    const float* __restrict__ ws_att,   // [128][8] this layer
    unsigned short* __restrict__ hm_bf, float* __restrict__ al_s,
    float* __restrict__ al_d, int N){
  __shared__ float s_att[DD*8];
  int t = threadIdx.x;
  for (int i = t; i < DD*8; i += 256) s_att[i] = ws_att[i];
  __syncthreads();
  int wave = t >> 6, lane = t & 63;
  int n = blockIdx.x*4 + wave;
  if (n >= N) return;
  int e0 = lane, e1 = lane + 64;
  float v0 = h[(size_t)n*DD + e0], v1 = h[(size_t)n*DD + e1];
  float sum = waveReduceSum(v0 + v1);
  float mu = sum * (1.f/128.f);
  float d0 = v0 - mu, d1 = v1 - mu;
  float vs = waveReduceSum(d0*d0 + d1*d1);
  float rstd = rsqrtf(vs*(1.f/128.f) + 1e-5f);
  float hn0 = d0*rstd*ln_scale[e0] + ln_bias[e0];
  float hn1 = d1*rstd*ln_scale[e1] + ln_bias[e1];
  float m0 = gamma[e0]*hn0 + beta[e0];
  float m1 = gamma[e1]*hn1 + beta[e1];
  hm_bf[(size_t)n*DD + e0] = f2bf(m0);
  hm_bf[(size_t)n*DD + e1] = f2bf(m1);
  #pragma unroll
  for (int j = 0; j < 8; j++){
    float a = m0*s_att[e0*8 + j] + m1*s_att[e1*8 + j];
    a = waveReduceSum(a);
    if (lane == 0){
      if (j < 4) al_s[n*4 + j] = a;
      else       al_d[n*4 + (j - 4)] = a;
    }
  }
}

// ---------------- edge-parallel attention logits in CSR order ----------------
__global__ __launch_bounds__(256) void edge_logit_kernel(
    const unsigned short* __restrict__ eap, const float* __restrict__ al_s,
    const float* __restrict__ al_d, const int* __restrict__ srcp,
    const int* __restrict__ dstp, const float* __restrict__ we_att, // [32][4]
    float* __restrict__ abuf, int E){
  __shared__ float4 swe[EFEAT];
  int t = threadIdx.x;
  if (t < EFEAT) swe[t] = *(const float4*)&we_att[t*4];
  __syncthreads();
  int p = blockIdx.x*256 + t;
  if (p >= E) return;
  int s = srcp[p], d = dstp[p];
  float4 as = *(const float4*)&al_s[(size_t)s*4];
  float4 ad = *(const float4*)&al_d[(size_t)d*4];
  float a0 = as.x + ad.x, a1 = as.y + ad.y, a2 = as.z + ad.z, a3 = as.w + ad.w;
  const uint4* ep = (const uint4*)(eap + (size_t)p*EFEAT);
  #pragma unroll
  for (int q = 0; q < 4; q++){
    uint4 u = ep[q];
    unsigned arr[4] = {u.x, u.y, u.z, u.w};
    #pragma unroll
    for (int j = 0; j < 4; j++){
      float x0 = bf2f((unsigned short)(arr[j] & 0xffff));
      float x1 = bf2f((unsigned short)(arr[j] >> 16));
      float4 w0 = swe[q*8 + j*2], w1 = swe[q*8 + j*2 + 1];
      a0 += x0*w0.x + x1*w1.x;
      a1 += x0*w0.y + x1*w1.y;
      a2 += x0*w0.z + x1*w1.z;
      a3 += x0*w0.w + x1*w1.w;
    }
  }
  *(float4*)&abuf[(size_t)p*4] = make_float4(lrelu(a0), lrelu(a1), lrelu(a2), lrelu(a3));
}

// ---------------- fused softmax + aggregation (block per node, 64 threads) ------------
__global__ __launch_bounds__(64) void aggregate3_kernel(
    const unsigned short* __restrict__ hm_bf, const float* __restrict__ abuf,
    const float* __restrict__ al_s, const float* __restrict__ al_d,
    const float* __restrict__ al_self4, const int* __restrict__ offs,
    const int* __restrict__ srcp, unsigned short* __restrict__ z, int N){
  int n = blockIdx.x, t = threadIdx.x;
  int beg = offs[n], end = offs[n + 1];
  float4 aslf = *(const float4*)al_self4;
  float4 asn = *(const float4*)&al_s[(size_t)n*4];
  float4 adn = *(const float4*)&al_d[(size_t)n*4];
  float s0 = lrelu(asn.x + adn.x + aslf.x);
  float s1 = lrelu(asn.y + adn.y + aslf.y);
  float s2 = lrelu(asn.z + adn.z + aslf.z);
  float s3 = lrelu(asn.w + adn.w + aslf.w);
  float m0 = s0, m1 = s1, m2 = s2, m3 = s3;
  for (int p = beg; p < end; p++){
    float4 a = *(const float4*)&abuf[(size_t)p*4];
    m0 = fmaxf(m0, a.x); m1 = fmaxf(m1, a.y);
    m2 = fmaxf(m2, a.z); m3 = fmaxf(m3, a.w);
  }
  float e0 = __expf(s0 - m0), e1 = __expf(s1 - m1);
  float e2 = __expf(s2 - m2), e3 = __expf(s3 - m3);
  ushort2 hv = *((const ushort2*)(hm_bf + (size_t)n*DD) + t);
  float h0 = bf2f(hv.x), h1 = bf2f(hv.y);
  float ac00 = e0*h0, ac01 = e0*h1;
  float ac10 = e1*h0, ac11 = e1*h1;
  float ac20 = e2*h0, ac21 = e2*h1;
  float ac30 = e3*h0, ac31 = e3*h1;
  float den0 = e0, den1 = e1, den2 = e2, den3 = e3;
  int s_next = (beg < end) ? srcp[beg] : 0;
  for (int p = beg; p < end; p++){
    int s = s_next;
    if (p + 1 < end) s_next = srcp[p + 1];
    float4 a = *(const float4*)&abuf[(size_t)p*4];
    float w0 = __expf(a.x - m0), w1 = __expf(a.y - m1);
    float w2 = __expf(a.z - m2), w3 = __expf(a.w - m3);
    ushort2 v2 = *((const ushort2*)(hm_bf + (size_t)s*DD) + t);
    float v0 = bf2f(v2.x), v1 = bf2f(v2.y);
    ac00 += w0*v0; ac01 += w0*v1;
    ac10 += w1*v0; ac11 += w1*v1;
    ac20 += w2*v0; ac21 += w2*v1;
    ac30 += w3*v0; ac31 += w3*v1;
    den0 += w0; den1 += w1; den2 += w2; den3 += w3;
  }
  float r0 = 1.f/(den0 + 1e-16f), r1 = 1.f/(den1 + 1e-16f);
  float r2 = 1.f/(den2 + 1e-16f), r3 = 1.f/(den3 + 1e-16f);
  size_t zb = (size_t)n*HDIM;
  ushort2* zp = (ushort2*)(z + zb);
  zp[0*64 + t] = make_ushort2(f2bf(ac00*r0), f2bf(ac01*r0));
  zp[1*64 + t] = make_ushort2(f2bf(ac10*r1), f2bf(ac11*r1));
  zp[2*64 + t] = make_ushort2(f2bf(ac20*r2), f2bf(ac21*r2));
  zp[3*64 + t] = make_ushort2(f2bf(ac30*r3), f2bf(ac31*r3));
}

// ---------------- edge head MLP (bf16 node payloads) ----------------
__global__ __launch_bounds__(256) void head_kernel(
    const unsigned short* __restrict__ p_src, const unsigned short* __restrict__ p_dst,
    const float* __restrict__ ea, const float* __restrict__ W1c,
    const float* __restrict__ W2, const float* __restrict__ b2,
    const int* __restrict__ srcA, const int* __restrict__ dstA,
    float* __restrict__ out, int E){
  __shared__ float sW[EFEAT][DD];
  __shared__ float sW2[DD];
  int t = threadIdx.x;
  for (int i = t; i < EFEAT*DD; i += 256) sW[i >> 7][i & 127] = W1c[i];
  if (t < DD) sW2[t] = W2[t];
  __syncthreads();
  int wave = t >> 6, lane = t & 63;
  int d0 = 2*lane, d1 = 2*lane + 1;
  for (int q = 0; q < 4; q++){
    int e = blockIdx.x*16 + wave*4 + q;
    if (e >= E) break;
    int s = srcA[e], dn = dstA[e];
    ushort2 us = *((const ushort2*)(p_src + (size_t)s*DD) + lane);
    ushort2 ud = *((const ushort2*)(p_dst + (size_t)dn*DD) + lane);
    float z0 = bf2f(us.x) + bf2f(ud.x);
    float z1 = bf2f(us.y) + bf2f(ud.y);
    #pragma unroll
    for (int f = 0; f < EFEAT; f++){
      float xv = ea[(size_t)e*EFEAT + f];
      z0 += xv*sW[f][d0]; z1 += xv*sW[f][d1];
    }
    z0 = fmaxf(z0, 0.f); z1 = fmaxf(z1, 0.f);
    float acc = waveReduceSum(z0*sW2[d0] + z1*sW2[d1]);
    if (lane == 0) out[e] = acc + b2[0];
  }
}

extern "C" void kernel_launch(void* const* d_in, const int* in_sizes, int n_in,
                              void* d_out, int out_size, void* d_ws, size_t ws_size,
                              hipStream_t stream){
  const float* x      = (const float*)d_in[0];
  const int*   eidx   = (const int*)d_in[1];
  const float* eattr  = (const float*)d_in[2];
  const float* gamma  = (const float*)d_in[3];
  const float* beta   = (const float*)d_in[4];
  const float* embW   = (const float*)d_in[5];
  const float* embB   = (const float*)d_in[6];
  const float* lnS    = (const float*)d_in[7];
  const float* lnB    = (const float*)d_in[8];
  const float* gatW   = (const float*)d_in[9];
  const float* attS   = (const float*)d_in[10];
  const float* attD   = (const float*)d_in[11];
  const float* gatWe  = (const float*)d_in[12];
  const float* attE   = (const float*)d_in[13];
  const float* gatB   = (const float*)d_in[14];
  const float* hW1    = (const float*)d_in[15];
  const float* hB1    = (const float*)d_in[16];
  const float* hW2    = (const float*)d_in[17];
  const float* hB2    = (const float*)d_in[18];
  float* out = (float*)d_out;

  int N = in_sizes[0] / DD;
  int E = in_sizes[1] / 2;
  int L = in_sizes[3] / DD;
  int Npad = (N + 63) & ~63;

  const int* srcA = eidx;
  const int* dstA = eidx + E;

  float* ws = (float*)d_ws;
  float* ea_sum  = ws + 0;
  float* we_att  = ws + 64;      // L*128
  float* al_self = ws + 1024;    // L*4
  float* ws_att  = ws + 2048;    // L*1024 -> ends 8192
  size_t o = 8192;
  int* deg    = (int*)(ws + o); o += N;
  int* offs   = (int*)(ws + o); o += N + 1;
  int* cursor = (int*)(ws + o); o += N;
  int* eid    = (int*)(ws + o); o += E;
  int* srcp   = (int*)(ws + o); o += E;
  int* dstp   = (int*)(ws + o); o += E;
  o = (o + 255) & ~(size_t)255;
  unsigned short* Bt = (unsigned short*)(ws + o); o += (size_t)L*DD*HDIM/2;
  float* h     = ws + o; o += (size_t)N*DD;
  unsigned short* hm_bf = (unsigned short*)(ws + o); o += (size_t)N*DD/2;
  float* al_s  = ws + o; o += (size_t)N*4;
  float* al_d  = ws + o; o += (size_t)N*4;
  unsigned short* eap = (unsigned short*)(ws + o); o += (size_t)E*EFEAT/2;
  float* abuf  = ws + o; o += (size_t)E*4;
  unsigned short* z = (unsigned short*)(ws + o); o += (size_t)Npad*HDIM/2;
  // head phase reuse: hm_bf and z are dead by then
  unsigned short* p_src = hm_bf;
  unsigned short* p_dst = z;

  hipMemsetAsync(ea_sum, 0, EFEAT*sizeof(float), stream);
  hipMemsetAsync(deg, 0, (size_t)N*sizeof(int), stream);
  ea_sum_kernel<<<256, 256, 0, stream>>>(eattr, ea_sum, E);
  hist_kernel<<<(E + 255)/256, 256, 0, stream>>>(dstA, deg, E);
  scan_kernel<<<1, 1024, 0, stream>>>(deg, offs, N);
  hipMemcpyAsync(cursor, offs, (size_t)N*sizeof(int), hipMemcpyDeviceToDevice, stream);
  scatter_kernel<<<(E + 255)/256, 256, 0, stream>>>(dstA, srcA, cursor, eid, srcp, dstp, E);
  eap_prep_kernel<<<(E*EFEAT + 255)/256, 256, 0, stream>>>(eattr, eid, eap, E*EFEAT);
  fold_ws_kernel<<<(L*DD*8 + 3)/4, 256, 0, stream>>>(gatW, attS, attD, ws_att, L);
  fold_we_kernel<<<(L*EFEAT*NHEAD + 3)/4, 256, 0, stream>>>(gatWe, attE, we_att, L);
  fold_self_kernel<<<1, 64, 0, stream>>>(we_att, ea_sum, 1.0f/(float)E, al_self, L);
  bt_prep_kernel<<<(L*DD*HDIM + 255)/256, 256, 0, stream>>>(gatW, Bt, L*DD*HDIM);
  linear128_kernel<<<(N + 63)/64, 256, 0, stream>>>(x, embW, embB, h, N);

  for (int l = 0; l < L; l++){
    ln_film_al_kernel<<<(N + 3)/4, 256, 0, stream>>>(h, lnS + l*DD, lnB + l*DD,
        gamma + l*DD, beta + l*DD, ws_att + (size_t)l*DD*8, hm_bf, al_s, al_d, N);
    edge_logit_kernel<<<(E + 255)/256, 256, 0, stream>>>(eap, al_s, al_d, srcp, dstp,
        we_att + (size_t)l*EFEAT*NHEAD, abuf, E);
    aggregate3_kernel<<<N, 64, 0, stream>>>(hm_bf, abuf, al_s, al_d,
        al_self + (size_t)l*NHEAD, offs, srcp, z, N);
    gemm_post_kernel<<<(N + 63)/64, 256, 0, stream>>>(z, Bt + (size_t)l*DD*HDIM,
        gatB + (size_t)l*DD, h, N);
  }

  linear128_bf16_kernel<<<(N + 63)/64, 256, 0, stream>>>(h, hW1, hB1, p_src, N);
  linear128_bf16_kernel<<<(N + 63)/64, 256, 0, stream>>>(h, hW1 + DD*DD, nullptr, p_dst, N);
  head_kernel<<<(E + 15)/16, 256, 0, stream>>>(p_src, p_dst, eattr, hW1 + 2*DD*DD,
      hW2, hB2, srcA, dstA, out, E);
}

// Round 5
// 1143.935 us; speedup vs baseline: 2.7310x; 1.1655x over previous
//
#include <hip/hip_runtime.h>

#define DD 128      // GNN_DIM == NODE_FEAT
#define HDIM 512    // H * D
#define EFEAT 32
#define NHEAD 4

typedef short s16x8 __attribute__((ext_vector_type(8)));
typedef float f32x4 __attribute__((ext_vector_type(4)));

__device__ __forceinline__ float lrelu(float x){ return x > 0.f ? x : 0.2f*x; }

__device__ __forceinline__ unsigned short f2bf(float f){
  unsigned u = __float_as_uint(f);
  unsigned r = (u + 0x7FFFu + ((u >> 16) & 1u)) >> 16;
  return (unsigned short)r;
}
__device__ __forceinline__ float bf2f(unsigned short u){
  return __uint_as_float(((unsigned)u) << 16);
}

__device__ __forceinline__ float waveReduceSum(float v){
  #pragma unroll
  for (int m = 1; m < 64; m <<= 1) v += __shfl_xor(v, m, 64);
  return v;
}
__device__ __forceinline__ float waveReduceMax(float v){
  #pragma unroll
  for (int m = 1; m < 64; m <<= 1) v = fmaxf(v, __shfl_xor(v, m, 64));
  return v;
}

// ---------------- edge-attr mean (sum, divided later) ----------------
__global__ void ea_sum_kernel(const float* __restrict__ ea, float* __restrict__ ea_sum, int E){
  __shared__ float s[EFEAT];
  int t = threadIdx.x;
  if (t < EFEAT) s[t] = 0.f;
  __syncthreads();
  int f = t & 31;
  int g = t >> 5;
  float acc = 0.f;
  for (int e = blockIdx.x*8 + g; e < E; e += gridDim.x*8)
    acc += ea[(size_t)e*EFEAT + f];
  atomicAdd(&s[f], acc);
  __syncthreads();
  if (t < EFEAT) atomicAdd(&ea_sum[t], s[t]);
}

// ---------------- CSR build over dst ----------------
__global__ void hist_kernel(const int* __restrict__ dst, int* __restrict__ deg, int E){
  int e = blockIdx.x*blockDim.x + threadIdx.x;
  if (e < E) atomicAdd(&deg[dst[e]], 1);
}

__global__ void scan_kernel(const int* __restrict__ deg, int* __restrict__ offs, int N){
  __shared__ int s[1024];
  int t = threadIdx.x;
  int chunk = (N + 1023) >> 10;
  int b = t*chunk, e = min(b + chunk, N);
  int sum = 0;
  for (int i = b; i < e; i++) sum += deg[i];
  s[t] = sum;
  __syncthreads();
  for (int d = 1; d < 1024; d <<= 1){
    int x = (t >= d) ? s[t - d] : 0;
    __syncthreads();
    s[t] += x;
    __syncthreads();
  }
  int run = s[t] - sum;   // exclusive prefix
  for (int i = b; i < e; i++){ offs[i] = run; run += deg[i]; }
  if (t == 1023) offs[N] = s[1023];
}

__global__ void scatter_kernel(const int* __restrict__ dst, const int* __restrict__ src,
                               int* __restrict__ cursor, int* __restrict__ eid,
                               int* __restrict__ srcp, int* __restrict__ dstp,
                               int* __restrict__ posOf, int E){
  int e = blockIdx.x*blockDim.x + threadIdx.x;
  if (e < E){
    int d = dst[e];
    int p = atomicAdd(&cursor[d], 1);
    eid[p] = e;
    srcp[p] = src[e];
    dstp[p] = d;
    posOf[e] = p;
  }
}

// ---------------- permute+convert edge attrs into CSR order (bf16) ----------------
__global__ void eap_prep_kernel(const float* __restrict__ ea, const int* __restrict__ eid,
                                unsigned short* __restrict__ eap, int total){
  int idx = blockIdx.x*blockDim.x + threadIdx.x;
  if (idx >= total) return;
  int p = idx >> 5, f = idx & 31;
  eap[idx] = f2bf(ea[(size_t)eid[p]*EFEAT + f]);
}

// ---------------- parallel folds: wave per output ----------------
__global__ __launch_bounds__(256) void fold_ws_kernel(const float* __restrict__ gat_W,
    const float* __restrict__ att_src, const float* __restrict__ att_dst,
    float* __restrict__ ws_att, int L){
  int wave = threadIdx.x >> 6, lane = threadIdx.x & 63;
  int idx = blockIdx.x*4 + wave;
  if (idx >= L*DD*8) return;
  int j = idx & 7; int k = (idx >> 3) & 127; int l = idx >> 10;
  int h = j & 3;
  const float* att = (j < 4) ? att_src : att_dst;
  const float* av = att + (size_t)(l*NHEAD + h)*DD;
  const float* Wl = gat_W + (size_t)l*DD*HDIM + (size_t)k*HDIM + h*DD;
  float acc = Wl[lane]*av[lane] + Wl[lane + 64]*av[lane + 64];
  acc = waveReduceSum(acc);
  if (lane == 0) ws_att[idx] = acc;
}

__global__ __launch_bounds__(256) void fold_we_kernel(const float* __restrict__ gat_We,
    const float* __restrict__ att_edge, float* __restrict__ we_att, int L){
  int wave = threadIdx.x >> 6, lane = threadIdx.x & 63;
  int idx = blockIdx.x*4 + wave;
  if (idx >= L*EFEAT*NHEAD) return;
  int h = idx & 3; int f = (idx >> 2) & 31; int l = idx >> 7;
  const float* av = att_edge + (size_t)(l*NHEAD + h)*DD;
  const float* Wel = gat_We + (size_t)l*EFEAT*HDIM + (size_t)f*HDIM + h*DD;
  float acc = Wel[lane]*av[lane] + Wel[lane + 64]*av[lane + 64];
  acc = waveReduceSum(acc);
  if (lane == 0) we_att[idx] = acc;
}

__global__ void fold_self_kernel(const float* __restrict__ we_att,
    const float* __restrict__ ea_sum, float invE, float* __restrict__ al_self, int L){
  int t = threadIdx.x;
  if (t >= L*NHEAD) return;
  int h = t & 3; int l = t >> 2;
  float acc = 0.f;
  for (int f = 0; f < EFEAT; f++) acc += ea_sum[f]*invE * we_att[(l*EFEAT + f)*NHEAD + h];
  al_self[t] = acc;
}

// ---------------- transpose+convert gat_W to bf16 Bt[l][n=128][k=512] ----------------
__global__ void bt_prep_kernel(const float* __restrict__ gat_W,
                               unsigned short* __restrict__ Bt, int total){
  int i = blockIdx.x*blockDim.x + threadIdx.x;
  if (i >= total) return;
  int l = i >> 16; int rem = i & 65535;
  int d = rem >> 9; int kk = rem & 511;
  int k = kk & 127; int h = kk >> 7;
  Bt[i] = f2bf(gat_W[(size_t)l*DD*HDIM + (size_t)k*HDIM + h*DD + d]);
}

// ---------------- W1c -> MFMA B-fragment layout: Bh[c][lane][j] ----------------
// b-frag element j of lane (ln15,quad) for col-block c is W1c[k=quad*8+j][n=c*16+ln15]
__global__ void w1c_prep_kernel(const float* __restrict__ W1c, unsigned short* __restrict__ Bh){
  int i = blockIdx.x*blockDim.x + threadIdx.x;
  if (i >= 8*64*8) return;
  int j = i & 7, lane = (i >> 3) & 63, c = i >> 9;
  int ln15 = lane & 15, quad = lane >> 4;
  int k = quad*8 + j, n = c*16 + ln15;
  Bh[i] = f2bf(W1c[(size_t)k*DD + n]);
}

// ---------------- fp32 linear: C[M,128] = A[M,128] @ W[128,128] (+bias) ----------------
__global__ __launch_bounds__(256) void linear128_kernel(const float* __restrict__ A,
    const float* __restrict__ W, const float* __restrict__ bias,
    float* __restrict__ C, int M){
  constexpr int TM = 64;
  __shared__ float As[TM][DD];
  int t = threadIdx.x;
  int row0 = blockIdx.x*TM;
  for (int i = t; i < TM*DD; i += 256){
    int r = i >> 7, k = i & 127;
    int gr = row0 + r;
    As[r][k] = (gr < M) ? A[(size_t)gr*DD + k] : 0.f;
  }
  __syncthreads();
  int col = t & 127;
  int rbase = (t >> 7)*32;
  float acc0[32];
  #pragma unroll
  for (int r = 0; r < 32; r++) acc0[r] = 0.f;
  #pragma unroll 4
  for (int k = 0; k < DD; k++){
    float w0 = W[(size_t)k*DD + col];
    #pragma unroll
    for (int r = 0; r < 32; r++) acc0[r] += As[rbase + r][k]*w0;
  }
  float b0 = bias ? bias[col] : 0.f;
  for (int r = 0; r < 32; r++){
    int row = row0 + rbase + r;
    if (row < M) C[(size_t)row*DD + col] = acc0[r] + b0;
  }
}

// same, bf16 output
__global__ __launch_bounds__(256) void linear128_bf16_kernel(const float* __restrict__ A,
    const float* __restrict__ W, const float* __restrict__ bias,
    unsigned short* __restrict__ C, int M){
  constexpr int TM = 64;
  __shared__ float As[TM][DD];
  int t = threadIdx.x;
  int row0 = blockIdx.x*TM;
  for (int i = t; i < TM*DD; i += 256){
    int r = i >> 7, k = i & 127;
    int gr = row0 + r;
    As[r][k] = (gr < M) ? A[(size_t)gr*DD + k] : 0.f;
  }
  __syncthreads();
  int col = t & 127;
  int rbase = (t >> 7)*32;
  float acc0[32];
  #pragma unroll
  for (int r = 0; r < 32; r++) acc0[r] = 0.f;
  #pragma unroll 4
  for (int k = 0; k < DD; k++){
    float w0 = W[(size_t)k*DD + col];
    #pragma unroll
    for (int r = 0; r < 32; r++) acc0[r] += As[rbase + r][k]*w0;
  }
  float b0 = bias ? bias[col] : 0.f;
  for (int r = 0; r < 32; r++){
    int row = row0 + rbase + r;
    if (row < M) C[(size_t)row*DD + col] = f2bf(acc0[r] + b0);
  }
}

// ---------------- MFMA bf16 GEMM: h[N,128] = relu(0.25 * z[N,512] @ B + bias) ----------
__global__ __launch_bounds__(256) void gemm_post_kernel(
    const unsigned short* __restrict__ z, const unsigned short* __restrict__ Bt,
    const float* __restrict__ bias, float* __restrict__ hOut, int N){
  int t = threadIdx.x;
  int wave = t >> 6, lane = t & 63;
  int ln15 = lane & 15, quad = lane >> 4;
  int row0 = blockIdx.x*64 + wave*16;
  int arow = row0 + ln15;
  if (arow > N - 1) arow = N - 1;
  const unsigned short* aptr = z + (size_t)arow*HDIM + quad*8;
  const unsigned short* bptr = Bt + (size_t)ln15*HDIM + quad*8;

  f32x4 acc[8];
  #pragma unroll
  for (int c = 0; c < 8; c++) acc[c] = (f32x4)(0.f);

  #pragma unroll 4
  for (int ks = 0; ks < 16; ks++){
    s16x8 a = *(const s16x8*)(aptr + ks*32);
    #pragma unroll
    for (int c = 0; c < 8; c++){
      s16x8 b = *(const s16x8*)(bptr + (size_t)c*16*HDIM + ks*32);
      acc[c] = __builtin_amdgcn_mfma_f32_16x16x32_bf16(a, b, acc[c], 0, 0, 0);
    }
  }

  #pragma unroll
  for (int c = 0; c < 8; c++){
    int col = c*16 + ln15;
    float b0 = bias[col];
    #pragma unroll
    for (int r = 0; r < 4; r++){
      int row = row0 + quad*4 + r;
      if (row < N)
        hOut[(size_t)row*DD + col] = fmaxf(0.25f*acc[c][r] + b0, 0.f);
    }
  }
}

// ---------------- fused LayerNorm + FiLM + attention-logit projection ----------------
__global__ __launch_bounds__(256) void ln_film_al_kernel(const float* __restrict__ h,
    const float* __restrict__ ln_scale, const float* __restrict__ ln_bias,
    const float* __restrict__ gamma, const float* __restrict__ beta,
    const float* __restrict__ ws_att,   // [128][8] this layer
    unsigned short* __restrict__ hm_bf, float* __restrict__ al_s,
    float* __restrict__ al_d, int N){
  __shared__ float s_att[DD*8];
  int t = threadIdx.x;
  for (int i = t; i < DD*8; i += 256) s_att[i] = ws_att[i];
  __syncthreads();
  int wave = t >> 6, lane = t & 63;
  int n = blockIdx.x*4 + wave;
  if (n >= N) return;
  int e0 = lane, e1 = lane + 64;
  float v0 = h[(size_t)n*DD + e0], v1 = h[(size_t)n*DD + e1];
  float sum = waveReduceSum(v0 + v1);
  float mu = sum * (1.f/128.f);
  float d0 = v0 - mu, d1 = v1 - mu;
  float vs = waveReduceSum(d0*d0 + d1*d1);
  float rstd = rsqrtf(vs*(1.f/128.f) + 1e-5f);
  float hn0 = d0*rstd*ln_scale[e0] + ln_bias[e0];
  float hn1 = d1*rstd*ln_scale[e1] + ln_bias[e1];
  float m0 = gamma[e0]*hn0 + beta[e0];
  float m1 = gamma[e1]*hn1 + beta[e1];
  hm_bf[(size_t)n*DD + e0] = f2bf(m0);
  hm_bf[(size_t)n*DD + e1] = f2bf(m1);
  #pragma unroll
  for (int j = 0; j < 8; j++){
    float a = m0*s_att[e0*8 + j] + m1*s_att[e1*8 + j];
    a = waveReduceSum(a);
    if (lane == 0){
      if (j < 4) al_s[n*4 + j] = a;
      else       al_d[n*4 + (j - 4)] = a;
    }
  }
}

// ---------------- edge-parallel attention logits in CSR order ----------------
__global__ __launch_bounds__(256) void edge_logit_kernel(
    const unsigned short* __restrict__ eap, const float* __restrict__ al_s,
    const float* __restrict__ al_d, const int* __restrict__ srcp,
    const int* __restrict__ dstp, const float* __restrict__ we_att, // [32][4]
    float* __restrict__ abuf, int E){
  __shared__ float4 swe[EFEAT];
  int t = threadIdx.x;
  if (t < EFEAT) swe[t] = *(const float4*)&we_att[t*4];
  __syncthreads();
  int p = blockIdx.x*256 + t;
  if (p >= E) return;
  int s = srcp[p], d = dstp[p];
  float4 as = *(const float4*)&al_s[(size_t)s*4];
  float4 ad = *(const float4*)&al_d[(size_t)d*4];
  float a0 = as.x + ad.x, a1 = as.y + ad.y, a2 = as.z + ad.z, a3 = as.w + ad.w;
  const uint4* ep = (const uint4*)(eap + (size_t)p*EFEAT);
  #pragma unroll
  for (int q = 0; q < 4; q++){
    uint4 u = ep[q];
    unsigned arr[4] = {u.x, u.y, u.z, u.w};
    #pragma unroll
    for (int j = 0; j < 4; j++){
      float x0 = bf2f((unsigned short)(arr[j] & 0xffff));
      float x1 = bf2f((unsigned short)(arr[j] >> 16));
      float4 w0 = swe[q*8 + j*2], w1 = swe[q*8 + j*2 + 1];
      a0 += x0*w0.x + x1*w1.x;
      a1 += x0*w0.y + x1*w1.y;
      a2 += x0*w0.z + x1*w1.z;
      a3 += x0*w0.w + x1*w1.w;
    }
  }
  *(float4*)&abuf[(size_t)p*4] = make_float4(lrelu(a0), lrelu(a1), lrelu(a2), lrelu(a3));
}

// ---------------- fused softmax + aggregation (block per node, 64 threads) ------------
__global__ __launch_bounds__(64) void aggregate3_kernel(
    const unsigned short* __restrict__ hm_bf, const float* __restrict__ abuf,
    const float* __restrict__ al_s, const float* __restrict__ al_d,
    const float* __restrict__ al_self4, const int* __restrict__ offs,
    const int* __restrict__ srcp, unsigned short* __restrict__ z, int N){
  int n = blockIdx.x, t = threadIdx.x;
  int beg = offs[n], end = offs[n + 1];
  float4 aslf = *(const float4*)al_self4;
  float4 asn = *(const float4*)&al_s[(size_t)n*4];
  float4 adn = *(const float4*)&al_d[(size_t)n*4];
  float s0 = lrelu(asn.x + adn.x + aslf.x);
  float s1 = lrelu(asn.y + adn.y + aslf.y);
  float s2 = lrelu(asn.z + adn.z + aslf.z);
  float s3 = lrelu(asn.w + adn.w + aslf.w);
  // lane-parallel max pass
  float m0 = s0, m1 = s1, m2 = s2, m3 = s3;
  for (int p = beg + t; p < end; p += 64){
    float4 a = *(const float4*)&abuf[(size_t)p*4];
    m0 = fmaxf(m0, a.x); m1 = fmaxf(m1, a.y);
    m2 = fmaxf(m2, a.z); m3 = fmaxf(m3, a.w);
  }
  m0 = waveReduceMax(m0); m1 = waveReduceMax(m1);
  m2 = waveReduceMax(m2); m3 = waveReduceMax(m3);
  float e0 = __expf(s0 - m0), e1 = __expf(s1 - m1);
  float e2 = __expf(s2 - m2), e3 = __expf(s3 - m3);
  ushort2 hv = *((const ushort2*)(hm_bf + (size_t)n*DD) + t);
  float h0 = bf2f(hv.x), h1 = bf2f(hv.y);
  float ac00 = e0*h0, ac01 = e0*h1;
  float ac10 = e1*h0, ac11 = e1*h1;
  float ac20 = e2*h0, ac21 = e2*h1;
  float ac30 = e3*h0, ac31 = e3*h1;
  float den0 = e0, den1 = e1, den2 = e2, den3 = e3;
  int p = beg;
  for (; p + 2 <= end; p += 2){
    int sA = srcp[p], sB = srcp[p + 1];
    float4 aA = *(const float4*)&abuf[(size_t)p*4];
    float4 aB = *(const float4*)&abuf[(size_t)(p + 1)*4];
    ushort2 vA = *((const ushort2*)(hm_bf + (size_t)sA*DD) + t);
    ushort2 vB = *((const ushort2*)(hm_bf + (size_t)sB*DD) + t);
    float wA0 = __expf(aA.x - m0), wA1 = __expf(aA.y - m1);
    float wA2 = __expf(aA.z - m2), wA3 = __expf(aA.w - m3);
    float wB0 = __expf(aB.x - m0), wB1 = __expf(aB.y - m1);
    float wB2 = __expf(aB.z - m2), wB3 = __expf(aB.w - m3);
    float vA0 = bf2f(vA.x), vA1 = bf2f(vA.y);
    float vB0 = bf2f(vB.x), vB1 = bf2f(vB.y);
    ac00 += wA0*vA0 + wB0*vB0; ac01 += wA0*vA1 + wB0*vB1;
    ac10 += wA1*vA0 + wB1*vB0; ac11 += wA1*vA1 + wB1*vB1;
    ac20 += wA2*vA0 + wB2*vB0; ac21 += wA2*vA1 + wB2*vB1;
    ac30 += wA3*vA0 + wB3*vB0; ac31 += wA3*vA1 + wB3*vB1;
    den0 += wA0 + wB0; den1 += wA1 + wB1;
    den2 += wA2 + wB2; den3 += wA3 + wB3;
  }
  if (p < end){
    int s = srcp[p];
    float4 a = *(const float4*)&abuf[(size_t)p*4];
    ushort2 v2 = *((const ushort2*)(hm_bf + (size_t)s*DD) + t);
    float w0 = __expf(a.x - m0), w1 = __expf(a.y - m1);
    float w2 = __expf(a.z - m2), w3 = __expf(a.w - m3);
    float v0 = bf2f(v2.x), v1 = bf2f(v2.y);
    ac00 += w0*v0; ac01 += w0*v1;
    ac10 += w1*v0; ac11 += w1*v1;
    ac20 += w2*v0; ac21 += w2*v1;
    ac30 += w3*v0; ac31 += w3*v1;
    den0 += w0; den1 += w1; den2 += w2; den3 += w3;
  }
  float r0 = 1.f/(den0 + 1e-16f), r1 = 1.f/(den1 + 1e-16f);
  float r2 = 1.f/(den2 + 1e-16f), r3 = 1.f/(den3 + 1e-16f);
  size_t zb = (size_t)n*HDIM;
  ushort2* zp = (ushort2*)(z + zb);
  zp[0*64 + t] = make_ushort2(f2bf(ac00*r0), f2bf(ac01*r0));
  zp[1*64 + t] = make_ushort2(f2bf(ac10*r1), f2bf(ac11*r1));
  zp[2*64 + t] = make_ushort2(f2bf(ac20*r2), f2bf(ac21*r2));
  zp[3*64 + t] = make_ushort2(f2bf(ac30*r3), f2bf(ac31*r3));
}

// ---------------- MFMA edge head: out[e] = relu(ps[s]+pd[d]+ea@W1c)@W2 + b2 ------------
// Each wave: 16 edges. A = ea rows (via posOf -> CSR eap), B = W1c frags (Bh).
__global__ __launch_bounds__(256) void head_mfma_kernel(
    const unsigned short* __restrict__ eap, const int* __restrict__ posOf,
    const unsigned short* __restrict__ Bh,
    const unsigned short* __restrict__ p_src, const unsigned short* __restrict__ p_dst,
    const float* __restrict__ W2, const float* __restrict__ b2,
    const int* __restrict__ srcA, const int* __restrict__ dstA,
    float* __restrict__ out, int E){
  int t = threadIdx.x;
  int wave = t >> 6, lane = t & 63;
  int ln15 = lane & 15, quad = lane >> 4;
  int e0 = (blockIdx.x*4 + wave)*16;
  if (e0 >= E) return;
  int arow = e0 + ln15;
  if (arow > E - 1) arow = E - 1;
  int ap = posOf[arow];
  s16x8 a = *(const s16x8*)(eap + (size_t)ap*EFEAT + quad*8);
  f32x4 acc[8];
  #pragma unroll
  for (int c = 0; c < 8; c++){
    s16x8 b = *(const s16x8*)(Bh + ((size_t)c*64 + lane)*8);
    acc[c] = __builtin_amdgcn_mfma_f32_16x16x32_bf16(a, b, (f32x4)(0.f), 0, 0, 0);
  }
  // epilogue: rows e0+quad*4+r, cols c*16+ln15
  float w2v[8];
  #pragma unroll
  for (int c = 0; c < 8; c++) w2v[c] = W2[c*16 + ln15];
  float res[4];
  #pragma unroll
  for (int r = 0; r < 4; r++){
    int e = e0 + quad*4 + r;
    int ec = (e < E) ? e : E - 1;
    int s = srcA[ec], d = dstA[ec];
    const unsigned short* ps = p_src + (size_t)s*DD + ln15;
    const unsigned short* pd = p_dst + (size_t)d*DD + ln15;
    float sum = 0.f;
    #pragma unroll
    for (int c = 0; c < 8; c++){
      float q = acc[c][r] + bf2f(ps[c*16]) + bf2f(pd[c*16]);
      sum += fmaxf(q, 0.f) * w2v[c];
    }
    res[r] = sum;
  }
  #pragma unroll
  for (int r = 0; r < 4; r++){
    float v = res[r];
    v += __shfl_xor(v, 1, 64); v += __shfl_xor(v, 2, 64);
    v += __shfl_xor(v, 4, 64); v += __shfl_xor(v, 8, 64);
    res[r] = v;
  }
  if (ln15 == 0){
    float bb = b2[0];
    #pragma unroll
    for (int r = 0; r < 4; r++){
      int e = e0 + quad*4 + r;
      if (e < E) out[e] = res[r] + bb;
    }
  }
}

extern "C" void kernel_launch(void* const* d_in, const int* in_sizes, int n_in,
                              void* d_out, int out_size, void* d_ws, size_t ws_size,
                              hipStream_t stream){
  const float* x      = (const float*)d_in[0];
  const int*   eidx   = (const int*)d_in[1];
  const float* eattr  = (const float*)d_in[2];
  const float* gamma  = (const float*)d_in[3];
  const float* beta   = (const float*)d_in[4];
  const float* embW   = (const float*)d_in[5];
  const float* embB   = (const float*)d_in[6];
  const float* lnS    = (const float*)d_in[7];
  const float* lnB    = (const float*)d_in[8];
  const float* gatW   = (const float*)d_in[9];
  const float* attS   = (const float*)d_in[10];
  const float* attD   = (const float*)d_in[11];
  const float* gatWe  = (const float*)d_in[12];
  const float* attE   = (const float*)d_in[13];
  const float* gatB   = (const float*)d_in[14];
  const float* hW1    = (const float*)d_in[15];
  const float* hB1    = (const float*)d_in[16];
  const float* hW2    = (const float*)d_in[17];
  const float* hB2    = (const float*)d_in[18];
  float* out = (float*)d_out;

  int N = in_sizes[0] / DD;
  int E = in_sizes[1] / 2;
  int L = in_sizes[3] / DD;
  int Npad = (N + 63) & ~63;

  const int* srcA = eidx;
  const int* dstA = eidx + E;

  float* ws = (float*)d_ws;
  float* ea_sum  = ws + 0;
  float* we_att  = ws + 64;      // L*128
  float* al_self = ws + 1024;    // L*4
  float* ws_att  = ws + 2048;    // L*1024 -> ends 8192
  size_t o = 8192;
  int* deg    = (int*)(ws + o); o += N;
  int* offs   = (int*)(ws + o); o += N + 1;
  int* cursor = (int*)(ws + o); o += N;
  int* eid    = (int*)(ws + o); o += E;
  int* srcp   = (int*)(ws + o); o += E;
  int* dstp   = (int*)(ws + o); o += E;
  int* posOf  = (int*)(ws + o); o += E;
  o = (o + 255) & ~(size_t)255;
  unsigned short* Bt = (unsigned short*)(ws + o); o += (size_t)L*DD*HDIM/2;
  unsigned short* Bh = (unsigned short*)(ws + o); o += 8*64*8/2;
  float* h     = ws + o; o += (size_t)N*DD;
  unsigned short* hm_bf = (unsigned short*)(ws + o); o += (size_t)N*DD/2;
  float* al_s  = ws + o; o += (size_t)N*4;
  float* al_d  = ws + o; o += (size_t)N*4;
  unsigned short* eap = (unsigned short*)(ws + o); o += (size_t)E*EFEAT/2;
  float* abuf  = ws + o; o += (size_t)E*4;
  unsigned short* z = (unsigned short*)(ws + o); o += (size_t)Npad*HDIM/2;
  // head phase reuse: hm_bf and z are dead by then
  unsigned short* p_src = hm_bf;
  unsigned short* p_dst = z;

  hipMemsetAsync(ea_sum, 0, EFEAT*sizeof(float), stream);
  hipMemsetAsync(deg, 0, (size_t)N*sizeof(int), stream);
  ea_sum_kernel<<<256, 256, 0, stream>>>(eattr, ea_sum, E);
  hist_kernel<<<(E + 255)/256, 256, 0, stream>>>(dstA, deg, E);
  scan_kernel<<<1, 1024, 0, stream>>>(deg, offs, N);
  hipMemcpyAsync(cursor, offs, (size_t)N*sizeof(int), hipMemcpyDeviceToDevice, stream);
  scatter_kernel<<<(E + 255)/256, 256, 0, stream>>>(dstA, srcA, cursor, eid, srcp, dstp,
                                                    posOf, E);
  eap_prep_kernel<<<(E*EFEAT + 255)/256, 256, 0, stream>>>(eattr, eid, eap, E*EFEAT);
  fold_ws_kernel<<<(L*DD*8 + 3)/4, 256, 0, stream>>>(gatW, attS, attD, ws_att, L);
  fold_we_kernel<<<(L*EFEAT*NHEAD + 3)/4, 256, 0, stream>>>(gatWe, attE, we_att, L);
  fold_self_kernel<<<1, 64, 0, stream>>>(we_att, ea_sum, 1.0f/(float)E, al_self, L);
  bt_prep_kernel<<<(L*DD*HDIM + 255)/256, 256, 0, stream>>>(gatW, Bt, L*DD*HDIM);
  w1c_prep_kernel<<<(8*64*8 + 255)/256, 256, 0, stream>>>(hW1 + 2*DD*DD, Bh);
  linear128_kernel<<<(N + 63)/64, 256, 0, stream>>>(x, embW, embB, h, N);

  for (int l = 0; l < L; l++){
    ln_film_al_kernel<<<(N + 3)/4, 256, 0, stream>>>(h, lnS + l*DD, lnB + l*DD,
        gamma + l*DD, beta + l*DD, ws_att + (size_t)l*DD*8, hm_bf, al_s, al_d, N);
    edge_logit_kernel<<<(E + 255)/256, 256, 0, stream>>>(eap, al_s, al_d, srcp, dstp,
        we_att + (size_t)l*EFEAT*NHEAD, abuf, E);
    aggregate3_kernel<<<N, 64, 0, stream>>>(hm_bf, abuf, al_s, al_d,
        al_self + (size_t)l*NHEAD, offs, srcp, z, N);
    gemm_post_kernel<<<(N + 63)/64, 256, 0, stream>>>(z, Bt + (size_t)l*DD*HDIM,
        gatB + (size_t)l*DD, h, N);
  }

  linear128_bf16_kernel<<<(N + 63)/64, 256, 0, stream>>>(h, hW1, hB1, p_src, N);
  linear128_bf16_kernel<<<(N + 63)/64, 256, 0, stream>>>(h, hW1 + DD*DD, nullptr, p_dst, N);
  head_mfma_kernel<<<(E + 63)/64, 256, 0, stream>>>(eap, posOf, Bh, p_src, p_dst,
      hW2, hB2, srcA, dstA, out, E);
}

// Round 6
// 967.980 us; speedup vs baseline: 3.2274x; 1.1818x over previous
//
#include <hip/hip_runtime.h>

#define DD 128      // GNN_DIM == NODE_FEAT
#define HDIM 512    // H * D
#define EFEAT 32
#define NHEAD 4

typedef short s16x8 __attribute__((ext_vector_type(8)));
typedef float f32x4 __attribute__((ext_vector_type(4)));

__device__ __forceinline__ float lrelu(float x){ return x > 0.f ? x : 0.2f*x; }

__device__ __forceinline__ unsigned short f2bf(float f){
  unsigned u = __float_as_uint(f);
  unsigned r = (u + 0x7FFFu + ((u >> 16) & 1u)) >> 16;
  return (unsigned short)r;
}
__device__ __forceinline__ float bf2f(unsigned short u){
  return __uint_as_float(((unsigned)u) << 16);
}

__device__ __forceinline__ float waveReduceSum(float v){
  #pragma unroll
  for (int m = 1; m < 64; m <<= 1) v += __shfl_xor(v, m, 64);
  return v;
}
__device__ __forceinline__ float waveReduceMax(float v){
  #pragma unroll
  for (int m = 1; m < 64; m <<= 1) v = fmaxf(v, __shfl_xor(v, m, 64));
  return v;
}
// reduction across the 16 lanes of one quad (ln15 bits)
__device__ __forceinline__ float quadReduceSum(float v){
  v += __shfl_xor(v, 1, 64); v += __shfl_xor(v, 2, 64);
  v += __shfl_xor(v, 4, 64); v += __shfl_xor(v, 8, 64);
  return v;
}

// ---------------- edge-attr column sums (float4, saturating grid) ----------------
__global__ __launch_bounds__(256) void ea_sum4_kernel(const float* __restrict__ ea,
                                                      float* __restrict__ ea_sum, int E){
  __shared__ float s[EFEAT];
  int t = threadIdx.x;
  if (t < EFEAT) s[t] = 0.f;
  __syncthreads();
  int nvec = E*8;
  float4 acc = make_float4(0.f, 0.f, 0.f, 0.f);
  for (int i = blockIdx.x*256 + t; i < nvec; i += gridDim.x*256){
    float4 v = *((const float4*)ea + i);
    acc.x += v.x; acc.y += v.y; acc.z += v.z; acc.w += v.w;
  }
  int cg = (t & 7)*4;    // stride (grid*256) is multiple of 8 -> column group fixed
  atomicAdd(&s[cg + 0], acc.x); atomicAdd(&s[cg + 1], acc.y);
  atomicAdd(&s[cg + 2], acc.z); atomicAdd(&s[cg + 3], acc.w);
  __syncthreads();
  if (t < EFEAT) atomicAdd(&ea_sum[t], s[t]);
}

// ---------------- CSR build over dst ----------------
__global__ void hist_kernel(const int* __restrict__ dst, int* __restrict__ deg, int E){
  int e = blockIdx.x*blockDim.x + threadIdx.x;
  if (e < E) atomicAdd(&deg[dst[e]], 1);
}

__global__ void scan_kernel(const int* __restrict__ deg, int* __restrict__ offs, int N){
  __shared__ int s[1024];
  int t = threadIdx.x;
  int chunk = (N + 1023) >> 10;
  int b = t*chunk, e = min(b + chunk, N);
  int sum = 0;
  for (int i = b; i < e; i++) sum += deg[i];
  s[t] = sum;
  __syncthreads();
  for (int d = 1; d < 1024; d <<= 1){
    int x = (t >= d) ? s[t - d] : 0;
    __syncthreads();
    s[t] += x;
    __syncthreads();
  }
  int run = s[t] - sum;   // exclusive prefix
  for (int i = b; i < e; i++){ offs[i] = run; run += deg[i]; }
  if (t == 1023) offs[N] = s[1023];
}

__global__ void scatter_kernel(const int* __restrict__ dst, const int* __restrict__ src,
                               int* __restrict__ cursor, int* __restrict__ eid,
                               int* __restrict__ srcp, int* __restrict__ dstp,
                               int* __restrict__ posOf, int E){
  int e = blockIdx.x*blockDim.x + threadIdx.x;
  if (e < E){
    int d = dst[e];
    int p = atomicAdd(&cursor[d], 1);
    eid[p] = e;
    srcp[p] = src[e];
    dstp[p] = d;
    posOf[e] = p;
  }
}

// ---------------- permute+convert edge attrs into CSR order (bf16, float4) ------------
__global__ void eap_prep_kernel(const float* __restrict__ ea, const int* __restrict__ eid,
                                unsigned short* __restrict__ eap, int E){
  int idx = blockIdx.x*blockDim.x + threadIdx.x;   // one thread per float4
  int p = idx >> 3, q = idx & 7;
  if (p >= E) return;
  float4 v = *((const float4*)(ea + (size_t)eid[p]*EFEAT) + q);
  ushort4 u = make_ushort4(f2bf(v.x), f2bf(v.y), f2bf(v.z), f2bf(v.w));
  *((ushort4*)(eap + (size_t)p*EFEAT) + q) = u;
}

// ---------------- parallel folds: wave per output ----------------
__global__ __launch_bounds__(256) void fold_ws_kernel(const float* __restrict__ gat_W,
    const float* __restrict__ att_src, const float* __restrict__ att_dst,
    float* __restrict__ ws_att, int L){
  int wave = threadIdx.x >> 6, lane = threadIdx.x & 63;
  int idx = blockIdx.x*4 + wave;
  if (idx >= L*DD*8) return;
  int j = idx & 7; int k = (idx >> 3) & 127; int l = idx >> 10;
  int h = j & 3;
  const float* att = (j < 4) ? att_src : att_dst;
  const float* av = att + (size_t)(l*NHEAD + h)*DD;
  const float* Wl = gat_W + (size_t)l*DD*HDIM + (size_t)k*HDIM + h*DD;
  float acc = Wl[lane]*av[lane] + Wl[lane + 64]*av[lane + 64];
  acc = waveReduceSum(acc);
  if (lane == 0) ws_att[idx] = acc;
}

__global__ __launch_bounds__(256) void fold_we_kernel(const float* __restrict__ gat_We,
    const float* __restrict__ att_edge, float* __restrict__ we_att, int L){
  int wave = threadIdx.x >> 6, lane = threadIdx.x & 63;
  int idx = blockIdx.x*4 + wave;
  if (idx >= L*EFEAT*NHEAD) return;
  int h = idx & 3; int f = (idx >> 2) & 31; int l = idx >> 7;
  const float* av = att_edge + (size_t)(l*NHEAD + h)*DD;
  const float* Wel = gat_We + (size_t)l*EFEAT*HDIM + (size_t)f*HDIM + h*DD;
  float acc = Wel[lane]*av[lane] + Wel[lane + 64]*av[lane + 64];
  acc = waveReduceSum(acc);
  if (lane == 0) we_att[idx] = acc;
}

__global__ void fold_self_kernel(const float* __restrict__ we_att,
    const float* __restrict__ ea_sum, float invE, float* __restrict__ al_self, int L){
  int t = threadIdx.x;
  if (t >= L*NHEAD) return;
  int h = t & 3; int l = t >> 2;
  float acc = 0.f;
  for (int f = 0; f < EFEAT; f++) acc += ea_sum[f]*invE * we_att[(l*EFEAT + f)*NHEAD + h];
  al_self[t] = acc;
}

// ---------------- transpose+convert gat_W to bf16 Bt[l][n=128][k=512] ----------------
__global__ void bt_prep_kernel(const float* __restrict__ gat_W,
                               unsigned short* __restrict__ Bt, int total){
  int i = blockIdx.x*blockDim.x + threadIdx.x;
  if (i >= total) return;
  int l = i >> 16; int rem = i & 65535;
  int d = rem >> 9; int kk = rem & 511;
  int k = kk & 127; int h = kk >> 7;
  Bt[i] = f2bf(gat_W[(size_t)l*DD*HDIM + (size_t)k*HDIM + h*DD + d]);
}

// ---------------- W1c -> MFMA B-fragment layout: Bh[c][lane][j] ----------------
__global__ void w1c_prep_kernel(const float* __restrict__ W1c, unsigned short* __restrict__ Bh){
  int i = blockIdx.x*blockDim.x + threadIdx.x;
  if (i >= 8*64*8) return;
  int j = i & 7, lane = (i >> 3) & 63, c = i >> 9;
  int ln15 = lane & 15, quad = lane >> 4;
  int k = quad*8 + j, n = c*16 + ln15;
  Bh[i] = f2bf(W1c[(size_t)k*DD + n]);
}

// ---------------- fp32 linear: C[M,128] = A[M,128] @ W[128,128] (+bias) ----------------
__global__ __launch_bounds__(256) void linear128_kernel(const float* __restrict__ A,
    const float* __restrict__ W, const float* __restrict__ bias,
    float* __restrict__ C, int M){
  constexpr int TM = 64;
  __shared__ float As[TM][DD];
  int t = threadIdx.x;
  int row0 = blockIdx.x*TM;
  for (int i = t; i < TM*DD; i += 256){
    int r = i >> 7, k = i & 127;
    int gr = row0 + r;
    As[r][k] = (gr < M) ? A[(size_t)gr*DD + k] : 0.f;
  }
  __syncthreads();
  int col = t & 127;
  int rbase = (t >> 7)*32;
  float acc0[32];
  #pragma unroll
  for (int r = 0; r < 32; r++) acc0[r] = 0.f;
  #pragma unroll 4
  for (int k = 0; k < DD; k++){
    float w0 = W[(size_t)k*DD + col];
    #pragma unroll
    for (int r = 0; r < 32; r++) acc0[r] += As[rbase + r][k]*w0;
  }
  float b0 = bias ? bias[col] : 0.f;
  for (int r = 0; r < 32; r++){
    int row = row0 + rbase + r;
    if (row < M) C[(size_t)row*DD + col] = acc0[r] + b0;
  }
}

// same, bf16 output
__global__ __launch_bounds__(256) void linear128_bf16_kernel(const float* __restrict__ A,
    const float* __restrict__ W, const float* __restrict__ bias,
    unsigned short* __restrict__ C, int M){
  constexpr int TM = 64;
  __shared__ float As[TM][DD];
  int t = threadIdx.x;
  int row0 = blockIdx.x*TM;
  for (int i = t; i < TM*DD; i += 256){
    int r = i >> 7, k = i & 127;
    int gr = row0 + r;
    As[r][k] = (gr < M) ? A[(size_t)gr*DD + k] : 0.f;
  }
  __syncthreads();
  int col = t & 127;
  int rbase = (t >> 7)*32;
  float acc0[32];
  #pragma unroll
  for (int r = 0; r < 32; r++) acc0[r] = 0.f;
  #pragma unroll 4
  for (int k = 0; k < DD; k++){
    float w0 = W[(size_t)k*DD + col];
    #pragma unroll
    for (int r = 0; r < 32; r++) acc0[r] += As[rbase + r][k]*w0;
  }
  float b0 = bias ? bias[col] : 0.f;
  for (int r = 0; r < 32; r++){
    int row = row0 + rbase + r;
    if (row < M) C[(size_t)row*DD + col] = f2bf(acc0[r] + b0);
  }
}

// ---------------- MFMA GEMM + fused LN/FiLM/att-logit epilogue ----------------
// acc = 0.25 * z[N,512] @ B + bias; hrow = relu(acc)
// mode 0: LN+FiLM -> hm_bf, al_s, al_d (next layer params)
// mode 1: write hrow to hOut (final layer)
__global__ __launch_bounds__(256) void gemm_ln_kernel(
    const unsigned short* __restrict__ z, const unsigned short* __restrict__ Bt,
    const float* __restrict__ bias,
    const float* __restrict__ ln_scale, const float* __restrict__ ln_bias,
    const float* __restrict__ gamma, const float* __restrict__ beta,
    const float* __restrict__ ws_att,
    unsigned short* __restrict__ hm_bf, float* __restrict__ al_s,
    float* __restrict__ al_d, float* __restrict__ hOut, int N, int mode){
  __shared__ float s_att[DD*8];
  __shared__ float sP[4][DD];   // ln_scale, ln_bias, gamma, beta
  int t = threadIdx.x;
  if (mode == 0){
    for (int i = t; i < DD*8; i += 256) s_att[i] = ws_att[i];
    for (int i = t; i < DD; i += 256){
      sP[0][i] = ln_scale[i]; sP[1][i] = ln_bias[i];
      sP[2][i] = gamma[i];    sP[3][i] = beta[i];
    }
    __syncthreads();
  }
  int wave = t >> 6, lane = t & 63;
  int ln15 = lane & 15, quad = lane >> 4;
  int row0 = blockIdx.x*64 + wave*16;
  int arow = row0 + ln15;
  if (arow > N - 1) arow = N - 1;
  const unsigned short* aptr = z + (size_t)arow*HDIM + quad*8;
  const unsigned short* bptr = Bt + (size_t)ln15*HDIM + quad*8;

  f32x4 acc[8];
  #pragma unroll
  for (int c = 0; c < 8; c++) acc[c] = (f32x4)(0.f);

  #pragma unroll 4
  for (int ks = 0; ks < 16; ks++){
    s16x8 a = *(const s16x8*)(aptr + ks*32);
    #pragma unroll
    for (int c = 0; c < 8; c++){
      s16x8 b = *(const s16x8*)(bptr + (size_t)c*16*HDIM + ks*32);
      acc[c] = __builtin_amdgcn_mfma_f32_16x16x32_bf16(a, b, acc[c], 0, 0, 0);
    }
  }

  float bv[8];
  #pragma unroll
  for (int c = 0; c < 8; c++) bv[c] = bias[c*16 + ln15];

  #pragma unroll
  for (int r = 0; r < 4; r++){
    int row = row0 + quad*4 + r;
    bool valid = (row < N);
    float hv[8];
    #pragma unroll
    for (int c = 0; c < 8; c++) hv[c] = fmaxf(0.25f*acc[c][r] + bv[c], 0.f);
    if (mode == 1){
      if (valid){
        #pragma unroll
        for (int c = 0; c < 8; c++) hOut[(size_t)row*DD + c*16 + ln15] = hv[c];
      }
      continue;
    }
    // LayerNorm over the 128 cols of this row (held by the 16 lanes of this quad)
    float sum = 0.f;
    #pragma unroll
    for (int c = 0; c < 8; c++) sum += hv[c];
    sum = quadReduceSum(sum);
    float mu = sum * (1.f/128.f);
    float vs = 0.f;
    #pragma unroll
    for (int c = 0; c < 8; c++){ float d = hv[c] - mu; vs += d*d; }
    vs = quadReduceSum(vs);
    float rstd = rsqrtf(vs*(1.f/128.f) + 1e-5f);
    float m[8];
    #pragma unroll
    for (int c = 0; c < 8; c++){
      int col = c*16 + ln15;
      float hn = (hv[c] - mu)*rstd*sP[0][col] + sP[1][col];
      m[c] = sP[2][col]*hn + sP[3][col];
      if (valid) hm_bf[(size_t)row*DD + col] = f2bf(m[c]);
    }
    float alv[8];
    #pragma unroll
    for (int j = 0; j < 8; j++){
      float a = 0.f;
      #pragma unroll
      for (int c = 0; c < 8; c++) a += m[c]*s_att[(c*16 + ln15)*8 + j];
      alv[j] = quadReduceSum(a);
    }
    if (ln15 == 0 && valid){
      *(float4*)&al_s[(size_t)row*4] = make_float4(alv[0], alv[1], alv[2], alv[3]);
      *(float4*)&al_d[(size_t)row*4] = make_float4(alv[4], alv[5], alv[6], alv[7]);
    }
  }
}

// ---------------- standalone LayerNorm + FiLM + att-logit (layer 0) ----------------
__global__ __launch_bounds__(256) void ln_film_al_kernel(const float* __restrict__ h,
    const float* __restrict__ ln_scale, const float* __restrict__ ln_bias,
    const float* __restrict__ gamma, const float* __restrict__ beta,
    const float* __restrict__ ws_att,
    unsigned short* __restrict__ hm_bf, float* __restrict__ al_s,
    float* __restrict__ al_d, int N){
  __shared__ float s_att[DD*8];
  int t = threadIdx.x;
  for (int i = t; i < DD*8; i += 256) s_att[i] = ws_att[i];
  __syncthreads();
  int wave = t >> 6, lane = t & 63;
  int n = blockIdx.x*4 + wave;
  if (n >= N) return;
  int e0 = lane, e1 = lane + 64;
  float v0 = h[(size_t)n*DD + e0], v1 = h[(size_t)n*DD + e1];
  float sum = waveReduceSum(v0 + v1);
  float mu = sum * (1.f/128.f);
  float d0 = v0 - mu, d1 = v1 - mu;
  float vs = waveReduceSum(d0*d0 + d1*d1);
  float rstd = rsqrtf(vs*(1.f/128.f) + 1e-5f);
  float hn0 = d0*rstd*ln_scale[e0] + ln_bias[e0];
  float hn1 = d1*rstd*ln_scale[e1] + ln_bias[e1];
  float m0 = gamma[e0]*hn0 + beta[e0];
  float m1 = gamma[e1]*hn1 + beta[e1];
  hm_bf[(size_t)n*DD + e0] = f2bf(m0);
  hm_bf[(size_t)n*DD + e1] = f2bf(m1);
  #pragma unroll
  for (int j = 0; j < 8; j++){
    float a = m0*s_att[e0*8 + j] + m1*s_att[e1*8 + j];
    a = waveReduceSum(a);
    if (lane == 0){
      if (j < 4) al_s[n*4 + j] = a;
      else       al_d[n*4 + (j - 4)] = a;
    }
  }
}

// ---------------- edge-parallel attention logits in CSR order ----------------
__global__ __launch_bounds__(256) void edge_logit_kernel(
    const unsigned short* __restrict__ eap, const float* __restrict__ al_s,
    const float* __restrict__ al_d, const int* __restrict__ srcp,
    const int* __restrict__ dstp, const float* __restrict__ we_att, // [32][4]
    float* __restrict__ abuf, int E){
  __shared__ float4 swe[EFEAT];
  int t = threadIdx.x;
  if (t < EFEAT) swe[t] = *(const float4*)&we_att[t*4];
  __syncthreads();
  int p = blockIdx.x*256 + t;
  if (p >= E) return;
  int s = srcp[p], d = dstp[p];
  float4 as = *(const float4*)&al_s[(size_t)s*4];
  float4 ad = *(const float4*)&al_d[(size_t)d*4];
  float a0 = as.x + ad.x, a1 = as.y + ad.y, a2 = as.z + ad.z, a3 = as.w + ad.w;
  const uint4* ep = (const uint4*)(eap + (size_t)p*EFEAT);
  #pragma unroll
  for (int q = 0; q < 4; q++){
    uint4 u = ep[q];
    unsigned arr[4] = {u.x, u.y, u.z, u.w};
    #pragma unroll
    for (int j = 0; j < 4; j++){
      float x0 = bf2f((unsigned short)(arr[j] & 0xffff));
      float x1 = bf2f((unsigned short)(arr[j] >> 16));
      float4 w0 = swe[q*8 + j*2], w1 = swe[q*8 + j*2 + 1];
      a0 += x0*w0.x + x1*w1.x;
      a1 += x0*w0.y + x1*w1.y;
      a2 += x0*w0.z + x1*w1.z;
      a3 += x0*w0.w + x1*w1.w;
    }
  }
  *(float4*)&abuf[(size_t)p*4] = make_float4(lrelu(a0), lrelu(a1), lrelu(a2), lrelu(a3));
}

// ---------------- fused softmax + aggregation (block per node, 64 threads) ------------
__global__ __launch_bounds__(64) void aggregate3_kernel(
    const unsigned short* __restrict__ hm_bf, const float* __restrict__ abuf,
    const float* __restrict__ al_s, const float* __restrict__ al_d,
    const float* __restrict__ al_self4, const int* __restrict__ offs,
    const int* __restrict__ srcp, unsigned short* __restrict__ z, int N){
  int n = blockIdx.x, t = threadIdx.x;
  int beg = offs[n], end = offs[n + 1];
  float4 aslf = *(const float4*)al_self4;
  float4 asn = *(const float4*)&al_s[(size_t)n*4];
  float4 adn = *(const float4*)&al_d[(size_t)n*4];
  float s0 = lrelu(asn.x + adn.x + aslf.x);
  float s1 = lrelu(asn.y + adn.y + aslf.y);
  float s2 = lrelu(asn.z + adn.z + aslf.z);
  float s3 = lrelu(asn.w + adn.w + aslf.w);
  float m0 = s0, m1 = s1, m2 = s2, m3 = s3;
  for (int p = beg + t; p < end; p += 64){
    float4 a = *(const float4*)&abuf[(size_t)p*4];
    m0 = fmaxf(m0, a.x); m1 = fmaxf(m1, a.y);
    m2 = fmaxf(m2, a.z); m3 = fmaxf(m3, a.w);
  }
  m0 = waveReduceMax(m0); m1 = waveReduceMax(m1);
  m2 = waveReduceMax(m2); m3 = waveReduceMax(m3);
  float e0 = __expf(s0 - m0), e1 = __expf(s1 - m1);
  float e2 = __expf(s2 - m2), e3 = __expf(s3 - m3);
  ushort2 hv = *((const ushort2*)(hm_bf + (size_t)n*DD) + t);
  float h0 = bf2f(hv.x), h1 = bf2f(hv.y);
  float ac00 = e0*h0, ac01 = e0*h1;
  float ac10 = e1*h0, ac11 = e1*h1;
  float ac20 = e2*h0, ac21 = e2*h1;
  float ac30 = e3*h0, ac31 = e3*h1;
  float den0 = e0, den1 = e1, den2 = e2, den3 = e3;
  int p = beg;
  for (; p + 2 <= end; p += 2){
    int sA = srcp[p], sB = srcp[p + 1];
    float4 aA = *(const float4*)&abuf[(size_t)p*4];
    float4 aB = *(const float4*)&abuf[(size_t)(p + 1)*4];
    ushort2 vA = *((const ushort2*)(hm_bf + (size_t)sA*DD) + t);
    ushort2 vB = *((const ushort2*)(hm_bf + (size_t)sB*DD) + t);
    float wA0 = __expf(aA.x - m0), wA1 = __expf(aA.y - m1);
    float wA2 = __expf(aA.z - m2), wA3 = __expf(aA.w - m3);
    float wB0 = __expf(aB.x - m0), wB1 = __expf(aB.y - m1);
    float wB2 = __expf(aB.z - m2), wB3 = __expf(aB.w - m3);
    float vA0 = bf2f(vA.x), vA1 = bf2f(vA.y);
    float vB0 = bf2f(vB.x), vB1 = bf2f(vB.y);
    ac00 += wA0*vA0 + wB0*vB0; ac01 += wA0*vA1 + wB0*vB1;
    ac10 += wA1*vA0 + wB1*vB0; ac11 += wA1*vA1 + wB1*vB1;
    ac20 += wA2*vA0 + wB2*vB0; ac21 += wA2*vA1 + wB2*vB1;
    ac30 += wA3*vA0 + wB3*vB0; ac31 += wA3*vA1 + wB3*vB1;
    den0 += wA0 + wB0; den1 += wA1 + wB1;
    den2 += wA2 + wB2; den3 += wA3 + wB3;
  }
  if (p < end){
    int s = srcp[p];
    float4 a = *(const float4*)&abuf[(size_t)p*4];
    ushort2 v2 = *((const ushort2*)(hm_bf + (size_t)s*DD) + t);
    float w0 = __expf(a.x - m0), w1 = __expf(a.y - m1);
    float w2 = __expf(a.z - m2), w3 = __expf(a.w - m3);
    float v0 = bf2f(v2.x), v1 = bf2f(v2.y);
    ac00 += w0*v0; ac01 += w0*v1;
    ac10 += w1*v0; ac11 += w1*v1;
    ac20 += w2*v0; ac21 += w2*v1;
    ac30 += w3*v0; ac31 += w3*v1;
    den0 += w0; den1 += w1; den2 += w2; den3 += w3;
  }
  float r0 = 1.f/(den0 + 1e-16f), r1 = 1.f/(den1 + 1e-16f);
  float r2 = 1.f/(den2 + 1e-16f), r3 = 1.f/(den3 + 1e-16f);
  size_t zb = (size_t)n*HDIM;
  ushort2* zp = (ushort2*)(z + zb);
  zp[0*64 + t] = make_ushort2(f2bf(ac00*r0), f2bf(ac01*r0));
  zp[1*64 + t] = make_ushort2(f2bf(ac10*r1), f2bf(ac11*r1));
  zp[2*64 + t] = make_ushort2(f2bf(ac20*r2), f2bf(ac21*r2));
  zp[3*64 + t] = make_ushort2(f2bf(ac30*r3), f2bf(ac31*r3));
}

// ---------------- MFMA edge head: out[e] = relu(ps[s]+pd[d]+ea@W1c)@W2 + b2 ------------
__global__ __launch_bounds__(256) void head_mfma_kernel(
    const unsigned short* __restrict__ eap, const int* __restrict__ posOf,
    const unsigned short* __restrict__ Bh,
    const unsigned short* __restrict__ p_src, const unsigned short* __restrict__ p_dst,
    const float* __restrict__ W2, const float* __restrict__ b2,
    const int* __restrict__ srcA, const int* __restrict__ dstA,
    float* __restrict__ out, int E){
  int t = threadIdx.x;
  int wave = t >> 6, lane = t & 63;
  int ln15 = lane & 15, quad = lane >> 4;
  int e0 = (blockIdx.x*4 + wave)*16;
  if (e0 >= E) return;
  int arow = e0 + ln15;
  if (arow > E - 1) arow = E - 1;
  int ap = posOf[arow];
  s16x8 a = *(const s16x8*)(eap + (size_t)ap*EFEAT + quad*8);
  f32x4 acc[8];
  #pragma unroll
  for (int c = 0; c < 8; c++){
    s16x8 b = *(const s16x8*)(Bh + ((size_t)c*64 + lane)*8);
    acc[c] = __builtin_amdgcn_mfma_f32_16x16x32_bf16(a, b, (f32x4)(0.f), 0, 0, 0);
  }
  float w2v[8];
  #pragma unroll
  for (int c = 0; c < 8; c++) w2v[c] = W2[c*16 + ln15];
  float res[4];
  #pragma unroll
  for (int r = 0; r < 4; r++){
    int e = e0 + quad*4 + r;
    int ec = (e < E) ? e : E - 1;
    int s = srcA[ec], d = dstA[ec];
    const unsigned short* ps = p_src + (size_t)s*DD + ln15;
    const unsigned short* pd = p_dst + (size_t)d*DD + ln15;
    float sum = 0.f;
    #pragma unroll
    for (int c = 0; c < 8; c++){
      float q = acc[c][r] + bf2f(ps[c*16]) + bf2f(pd[c*16]);
      sum += fmaxf(q, 0.f) * w2v[c];
    }
    res[r] = sum;
  }
  #pragma unroll
  for (int r = 0; r < 4; r++){
    float v = res[r];
    v += __shfl_xor(v, 1, 64); v += __shfl_xor(v, 2, 64);
    v += __shfl_xor(v, 4, 64); v += __shfl_xor(v, 8, 64);
    res[r] = v;
  }
  if (ln15 == 0){
    float bb = b2[0];
    #pragma unroll
    for (int r = 0; r < 4; r++){
      int e = e0 + quad*4 + r;
      if (e < E) out[e] = res[r] + bb;
    }
  }
}

extern "C" void kernel_launch(void* const* d_in, const int* in_sizes, int n_in,
                              void* d_out, int out_size, void* d_ws, size_t ws_size,
                              hipStream_t stream){
  const float* x      = (const float*)d_in[0];
  const int*   eidx   = (const int*)d_in[1];
  const float* eattr  = (const float*)d_in[2];
  const float* gamma  = (const float*)d_in[3];
  const float* beta   = (const float*)d_in[4];
  const float* embW   = (const float*)d_in[5];
  const float* embB   = (const float*)d_in[6];
  const float* lnS    = (const float*)d_in[7];
  const float* lnB    = (const float*)d_in[8];
  const float* gatW   = (const float*)d_in[9];
  const float* attS   = (const float*)d_in[10];
  const float* attD   = (const float*)d_in[11];
  const float* gatWe  = (const float*)d_in[12];
  const float* attE   = (const float*)d_in[13];
  const float* gatB   = (const float*)d_in[14];
  const float* hW1    = (const float*)d_in[15];
  const float* hB1    = (const float*)d_in[16];
  const float* hW2    = (const float*)d_in[17];
  const float* hB2    = (const float*)d_in[18];
  float* out = (float*)d_out;

  int N = in_sizes[0] / DD;
  int E = in_sizes[1] / 2;
  int L = in_sizes[3] / DD;
  int Npad = (N + 63) & ~63;

  const int* srcA = eidx;
  const int* dstA = eidx + E;

  float* ws = (float*)d_ws;
  float* ea_sum  = ws + 0;
  float* we_att  = ws + 64;      // L*128
  float* al_self = ws + 1024;    // L*4
  float* ws_att  = ws + 2048;    // L*1024 -> ends 8192
  size_t o = 8192;
  int* deg    = (int*)(ws + o); o += N;
  int* offs   = (int*)(ws + o); o += N + 1;
  int* cursor = (int*)(ws + o); o += N;
  int* eid    = (int*)(ws + o); o += E;
  int* srcp   = (int*)(ws + o); o += E;
  int* dstp   = (int*)(ws + o); o += E;
  int* posOf  = (int*)(ws + o); o += E;
  o = (o + 255) & ~(size_t)255;
  unsigned short* Bt = (unsigned short*)(ws + o); o += (size_t)L*DD*HDIM/2;
  unsigned short* Bh = (unsigned short*)(ws + o); o += 8*64*8/2;
  float* h     = ws + o; o += (size_t)N*DD;
  unsigned short* hm_bf = (unsigned short*)(ws + o); o += (size_t)N*DD/2;
  float* al_s  = ws + o; o += (size_t)N*4;
  float* al_d  = ws + o; o += (size_t)N*4;
  unsigned short* eap = (unsigned short*)(ws + o); o += (size_t)E*EFEAT/2;
  float* abuf  = ws + o; o += (size_t)E*4;
  unsigned short* z = (unsigned short*)(ws + o); o += (size_t)Npad*HDIM/2;
  // head phase reuse: hm_bf and z are dead by then
  unsigned short* p_src = hm_bf;
  unsigned short* p_dst = z;

  hipMemsetAsync(ea_sum, 0, EFEAT*sizeof(float), stream);
  hipMemsetAsync(deg, 0, (size_t)N*sizeof(int), stream);
  ea_sum4_kernel<<<1024, 256, 0, stream>>>(eattr, ea_sum, E);
  hist_kernel<<<(E + 255)/256, 256, 0, stream>>>(dstA, deg, E);
  scan_kernel<<<1, 1024, 0, stream>>>(deg, offs, N);
  hipMemcpyAsync(cursor, offs, (size_t)N*sizeof(int), hipMemcpyDeviceToDevice, stream);
  scatter_kernel<<<(E + 255)/256, 256, 0, stream>>>(dstA, srcA, cursor, eid, srcp, dstp,
                                                    posOf, E);
  eap_prep_kernel<<<(E*8 + 255)/256, 256, 0, stream>>>(eattr, eid, eap, E);
  fold_ws_kernel<<<(L*DD*8 + 3)/4, 256, 0, stream>>>(gatW, attS, attD, ws_att, L);
  fold_we_kernel<<<(L*EFEAT*NHEAD + 3)/4, 256, 0, stream>>>(gatWe, attE, we_att, L);
  fold_self_kernel<<<1, 64, 0, stream>>>(we_att, ea_sum, 1.0f/(float)E, al_self, L);
  bt_prep_kernel<<<(L*DD*HDIM + 255)/256, 256, 0, stream>>>(gatW, Bt, L*DD*HDIM);
  w1c_prep_kernel<<<(8*64*8 + 255)/256, 256, 0, stream>>>(hW1 + 2*DD*DD, Bh);
  linear128_kernel<<<(N + 63)/64, 256, 0, stream>>>(x, embW, embB, h, N);
  ln_film_al_kernel<<<(N + 3)/4, 256, 0, stream>>>(h, lnS, lnB, gamma, beta,
      ws_att, hm_bf, al_s, al_d, N);

  for (int l = 0; l < L; l++){
    edge_logit_kernel<<<(E + 255)/256, 256, 0, stream>>>(eap, al_s, al_d, srcp, dstp,
        we_att + (size_t)l*EFEAT*NHEAD, abuf, E);
    aggregate3_kernel<<<N, 64, 0, stream>>>(hm_bf, abuf, al_s, al_d,
        al_self + (size_t)l*NHEAD, offs, srcp, z, N);
    if (l < L - 1){
      gemm_ln_kernel<<<(N + 63)/64, 256, 0, stream>>>(z, Bt + (size_t)l*DD*HDIM,
          gatB + (size_t)l*DD, lnS + (l+1)*DD, lnB + (l+1)*DD,
          gamma + (l+1)*DD, beta + (l+1)*DD, ws_att + (size_t)(l+1)*DD*8,
          hm_bf, al_s, al_d, nullptr, N, 0);
    } else {
      gemm_ln_kernel<<<(N + 63)/64, 256, 0, stream>>>(z, Bt + (size_t)l*DD*HDIM,
          gatB + (size_t)l*DD, nullptr, nullptr, nullptr, nullptr, nullptr,
          nullptr, nullptr, nullptr, h, N, 1);
    }
  }

  linear128_bf16_kernel<<<(N + 63)/64, 256, 0, stream>>>(h, hW1, hB1, p_src, N);
  linear128_bf16_kernel<<<(N + 63)/64, 256, 0, stream>>>(h, hW1 + DD*DD, nullptr, p_dst, N);
  head_mfma_kernel<<<(E + 63)/64, 256, 0, stream>>>(eap, posOf, Bh, p_src, p_dst,
      hW2, hB2, srcA, dstA, out, E);
}

// Round 7
// 851.573 us; speedup vs baseline: 3.6686x; 1.1367x over previous
//
#include <hip/hip_runtime.h>

#define DD 128      // GNN_DIM == NODE_FEAT
#define HDIM 512    // H * D
#define EFEAT 32
#define NHEAD 4

typedef short s16x8 __attribute__((ext_vector_type(8)));
typedef float f32x4 __attribute__((ext_vector_type(4)));

__device__ __forceinline__ float lrelu(float x){ return x > 0.f ? x : 0.2f*x; }

__device__ __forceinline__ unsigned short f2bf(float f){
  unsigned u = __float_as_uint(f);
  unsigned r = (u + 0x7FFFu + ((u >> 16) & 1u)) >> 16;
  return (unsigned short)r;
}
__device__ __forceinline__ float bf2f(unsigned short u){
  return __uint_as_float(((unsigned)u) << 16);
}

__device__ __forceinline__ float waveReduceSum(float v){
  #pragma unroll
  for (int m = 1; m < 64; m <<= 1) v += __shfl_xor(v, m, 64);
  return v;
}
__device__ __forceinline__ float waveReduceMax(float v){
  #pragma unroll
  for (int m = 1; m < 64; m <<= 1) v = fmaxf(v, __shfl_xor(v, m, 64));
  return v;
}
__device__ __forceinline__ float quadReduceSum(float v){
  v += __shfl_xor(v, 1, 64); v += __shfl_xor(v, 2, 64);
  v += __shfl_xor(v, 4, 64); v += __shfl_xor(v, 8, 64);
  return v;
}

// ---------------- edge-attr column sums (float4, saturating grid) ----------------
__global__ __launch_bounds__(256) void ea_sum4_kernel(const float* __restrict__ ea,
                                                      float* __restrict__ ea_sum, int E){
  __shared__ float s[EFEAT];
  int t = threadIdx.x;
  if (t < EFEAT) s[t] = 0.f;
  __syncthreads();
  int nvec = E*8;
  float4 acc = make_float4(0.f, 0.f, 0.f, 0.f);
  for (int i = blockIdx.x*256 + t; i < nvec; i += gridDim.x*256){
    float4 v = *((const float4*)ea + i);
    acc.x += v.x; acc.y += v.y; acc.z += v.z; acc.w += v.w;
  }
  int cg = (t & 7)*4;
  atomicAdd(&s[cg + 0], acc.x); atomicAdd(&s[cg + 1], acc.y);
  atomicAdd(&s[cg + 2], acc.z); atomicAdd(&s[cg + 3], acc.w);
  __syncthreads();
  if (t < EFEAT) atomicAdd(&ea_sum[t], s[t]);
}

// ---------------- CSR build over dst ----------------
__global__ void hist_kernel(const int* __restrict__ dst, int* __restrict__ deg, int E){
  int e = blockIdx.x*blockDim.x + threadIdx.x;
  if (e < E) atomicAdd(&deg[dst[e]], 1);
}

__global__ void scan_kernel(const int* __restrict__ deg, int* __restrict__ offs, int N){
  __shared__ int s[1024];
  int t = threadIdx.x;
  int chunk = (N + 1023) >> 10;
  int b = t*chunk, e = min(b + chunk, N);
  int sum = 0;
  for (int i = b; i < e; i++) sum += deg[i];
  s[t] = sum;
  __syncthreads();
  for (int d = 1; d < 1024; d <<= 1){
    int x = (t >= d) ? s[t - d] : 0;
    __syncthreads();
    s[t] += x;
    __syncthreads();
  }
  int run = s[t] - sum;
  for (int i = b; i < e; i++){ offs[i] = run; run += deg[i]; }
  if (t == 1023) offs[N] = s[1023];
}

__global__ void scatter_kernel(const int* __restrict__ dst, const int* __restrict__ src,
                               int* __restrict__ cursor, int* __restrict__ eid,
                               int* __restrict__ srcp, int* __restrict__ dstp,
                               int* __restrict__ posOf, int E){
  int e = blockIdx.x*blockDim.x + threadIdx.x;
  if (e < E){
    int d = dst[e];
    int p = atomicAdd(&cursor[d], 1);
    eid[p] = e;
    srcp[p] = src[e];
    dstp[p] = d;
    posOf[e] = p;
  }
}

// ---------------- permute+convert edge attrs into CSR order (bf16, float4) ------------
__global__ void eap_prep_kernel(const float* __restrict__ ea, const int* __restrict__ eid,
                                unsigned short* __restrict__ eap, int E){
  int idx = blockIdx.x*blockDim.x + threadIdx.x;
  int p = idx >> 3, q = idx & 7;
  if (p >= E) return;
  float4 v = *((const float4*)(ea + (size_t)eid[p]*EFEAT) + q);
  ushort4 u = make_ushort4(f2bf(v.x), f2bf(v.y), f2bf(v.z), f2bf(v.w));
  *((ushort4*)(eap + (size_t)p*EFEAT) + q) = u;
}

// ---------------- fp32 -> bf16 convert (float4 -> ushort4) ----------------
__global__ void bf16_conv_kernel(const float* __restrict__ in,
                                 unsigned short* __restrict__ out, int nvec){
  int i = blockIdx.x*blockDim.x + threadIdx.x;
  if (i >= nvec) return;
  float4 v = *((const float4*)in + i);
  *((ushort4*)out + i) = make_ushort4(f2bf(v.x), f2bf(v.y), f2bf(v.z), f2bf(v.w));
}

// ---------------- parallel folds: wave per output ----------------
__global__ __launch_bounds__(256) void fold_ws_kernel(const float* __restrict__ gat_W,
    const float* __restrict__ att_src, const float* __restrict__ att_dst,
    float* __restrict__ ws_att, int L){
  int wave = threadIdx.x >> 6, lane = threadIdx.x & 63;
  int idx = blockIdx.x*4 + wave;
  if (idx >= L*DD*8) return;
  int j = idx & 7; int k = (idx >> 3) & 127; int l = idx >> 10;
  int h = j & 3;
  const float* att = (j < 4) ? att_src : att_dst;
  const float* av = att + (size_t)(l*NHEAD + h)*DD;
  const float* Wl = gat_W + (size_t)l*DD*HDIM + (size_t)k*HDIM + h*DD;
  float acc = Wl[lane]*av[lane] + Wl[lane + 64]*av[lane + 64];
  acc = waveReduceSum(acc);
  if (lane == 0) ws_att[idx] = acc;
}

__global__ __launch_bounds__(256) void fold_we_kernel(const float* __restrict__ gat_We,
    const float* __restrict__ att_edge, float* __restrict__ we_att, int L){
  int wave = threadIdx.x >> 6, lane = threadIdx.x & 63;
  int idx = blockIdx.x*4 + wave;
  if (idx >= L*EFEAT*NHEAD) return;
  int h = idx & 3; int f = (idx >> 2) & 31; int l = idx >> 7;
  const float* av = att_edge + (size_t)(l*NHEAD + h)*DD;
  const float* Wel = gat_We + (size_t)l*EFEAT*HDIM + (size_t)f*HDIM + h*DD;
  float acc = Wel[lane]*av[lane] + Wel[lane + 64]*av[lane + 64];
  acc = waveReduceSum(acc);
  if (lane == 0) we_att[idx] = acc;
}

__global__ void fold_self_kernel(const float* __restrict__ we_att,
    const float* __restrict__ ea_sum, float invE, float* __restrict__ al_self, int L){
  int t = threadIdx.x;
  if (t >= L*NHEAD) return;
  int h = t & 3; int l = t >> 2;
  float acc = 0.f;
  for (int f = 0; f < EFEAT; f++) acc += ea_sum[f]*invE * we_att[(l*EFEAT + f)*NHEAD + h];
  al_self[t] = acc;
}

// ---------------- transpose+convert gat_W to bf16 Bt[l][n=128][k=512] ----------------
__global__ void bt_prep_kernel(const float* __restrict__ gat_W,
                               unsigned short* __restrict__ Bt, int total){
  int i = blockIdx.x*blockDim.x + threadIdx.x;
  if (i >= total) return;
  int l = i >> 16; int rem = i & 65535;
  int d = rem >> 9; int kk = rem & 511;
  int k = kk & 127; int h = kk >> 7;
  Bt[i] = f2bf(gat_W[(size_t)l*DD*HDIM + (size_t)k*HDIM + h*DD + d]);
}

// ---------------- embW -> bf16 transposed [128][128] ----------------
__global__ void embwt_prep_kernel(const float* __restrict__ embW,
                                  unsigned short* __restrict__ Wt){
  int i = blockIdx.x*blockDim.x + threadIdx.x;
  if (i >= DD*DD) return;
  int n = i >> 7, k = i & 127;
  Wt[i] = f2bf(embW[(size_t)k*DD + n]);
}

// ---------------- [W1a | W1b] -> bf16 transposed [256][128] ----------------
__global__ void w1ab_prep_kernel(const float* __restrict__ hW1,
                                 unsigned short* __restrict__ Bhd){
  int i = blockIdx.x*blockDim.x + threadIdx.x;
  if (i >= 256*DD) return;
  int n = i >> 7, k = i & 127;
  float v = (n < 128) ? hW1[(size_t)k*DD + n] : hW1[(size_t)(128 + k)*DD + (n - 128)];
  Bhd[i] = f2bf(v);
}

// ---------------- W1c -> MFMA B-fragment layout: Bh[c][lane][j] ----------------
__global__ void w1c_prep_kernel(const float* __restrict__ W1c, unsigned short* __restrict__ Bh){
  int i = blockIdx.x*blockDim.x + threadIdx.x;
  if (i >= 8*64*8) return;
  int j = i & 7, lane = (i >> 3) & 63, c = i >> 9;
  int ln15 = lane & 15, quad = lane >> 4;
  int k = quad*8 + j, n = c*16 + ln15;
  Bh[i] = f2bf(W1c[(size_t)k*DD + n]);
}

// ---------------- unified MFMA GEMM + fused epilogues ----------------
// C_acc = scale * A[N,KD] @ Bt^T + bias   (Bt is [NOUT][KD], bf16)
// relu flag applies relu; then:
//   mode 0 (NOUT==128 only): LN+FiLM -> hm_bf, al_s, al_d
//   mode 1: bf16 store to outbf[N,NOUT]
template<int KD, int NOUT>
__global__ __launch_bounds__(256) void gemm_fused_kernel(
    const unsigned short* __restrict__ A, const unsigned short* __restrict__ Bt,
    const float* __restrict__ bias, float scale, int relu, int mode,
    const float* __restrict__ ln_scale, const float* __restrict__ ln_bias,
    const float* __restrict__ gamma, const float* __restrict__ beta,
    const float* __restrict__ ws_att,
    unsigned short* __restrict__ hm_bf, float* __restrict__ al_s,
    float* __restrict__ al_d, unsigned short* __restrict__ outbf, int N){
  constexpr int NC = NOUT/16;
  __shared__ float s_att[DD*8];
  __shared__ float sP[4][DD];
  int t = threadIdx.x;
  if (mode == 0){
    for (int i = t; i < DD*8; i += 256) s_att[i] = ws_att[i];
    for (int i = t; i < DD; i += 256){
      sP[0][i] = ln_scale[i]; sP[1][i] = ln_bias[i];
      sP[2][i] = gamma[i];    sP[3][i] = beta[i];
    }
    __syncthreads();
  }
  int wave = t >> 6, lane = t & 63;
  int ln15 = lane & 15, quad = lane >> 4;
  int row0 = blockIdx.x*64 + wave*16;
  int arow = row0 + ln15;
  if (arow > N - 1) arow = N - 1;
  const unsigned short* aptr = A + (size_t)arow*KD + quad*8;

  f32x4 acc[NC];
  #pragma unroll
  for (int c = 0; c < NC; c++) acc[c] = (f32x4)(0.f);

  #pragma unroll
  for (int ks = 0; ks < KD/32; ks++){
    s16x8 a = *(const s16x8*)(aptr + ks*32);
    #pragma unroll
    for (int c = 0; c < NC; c++){
      s16x8 b = *(const s16x8*)(Bt + (size_t)(c*16 + ln15)*KD + quad*8 + ks*32);
      acc[c] = __builtin_amdgcn_mfma_f32_16x16x32_bf16(a, b, acc[c], 0, 0, 0);
    }
  }

  float bv[NC];
  #pragma unroll
  for (int c = 0; c < NC; c++){
    if constexpr (NOUT == 256) bv[c] = (c < 8) ? bias[c*16 + ln15] : 0.f;
    else bv[c] = bias[c*16 + ln15];
  }

  #pragma unroll
  for (int r = 0; r < 4; r++){
    int row = row0 + quad*4 + r;
    bool valid = (row < N);
    float hv[NC];
    #pragma unroll
    for (int c = 0; c < NC; c++){
      float v = scale*acc[c][r] + bv[c];
      hv[c] = relu ? fmaxf(v, 0.f) : v;
    }
    if (mode == 1){
      if (valid){
        #pragma unroll
        for (int c = 0; c < NC; c++)
          outbf[(size_t)row*NOUT + c*16 + ln15] = f2bf(hv[c]);
      }
      continue;
    }
    if constexpr (NOUT == 128){
      float sum = 0.f;
      #pragma unroll
      for (int c = 0; c < NC; c++) sum += hv[c];
      sum = quadReduceSum(sum);
      float mu = sum * (1.f/128.f);
      float vs = 0.f;
      #pragma unroll
      for (int c = 0; c < NC; c++){ float d = hv[c] - mu; vs += d*d; }
      vs = quadReduceSum(vs);
      float rstd = rsqrtf(vs*(1.f/128.f) + 1e-5f);
      float m[NC];
      #pragma unroll
      for (int c = 0; c < NC; c++){
        int col = c*16 + ln15;
        float hn = (hv[c] - mu)*rstd*sP[0][col] + sP[1][col];
        m[c] = sP[2][col]*hn + sP[3][col];
        if (valid) hm_bf[(size_t)row*DD + col] = f2bf(m[c]);
      }
      float alv[8];
      #pragma unroll
      for (int j = 0; j < 8; j++){
        float a = 0.f;
        #pragma unroll
        for (int c = 0; c < NC; c++) a += m[c]*s_att[(c*16 + ln15)*8 + j];
        alv[j] = quadReduceSum(a);
      }
      if (ln15 == 0 && valid){
        *(float4*)&al_s[(size_t)row*4] = make_float4(alv[0], alv[1], alv[2], alv[3]);
        *(float4*)&al_d[(size_t)row*4] = make_float4(alv[4], alv[5], alv[6], alv[7]);
      }
    }
  }
}

// ---------------- edge-parallel attention logits in CSR order ----------------
__global__ __launch_bounds__(256) void edge_logit_kernel(
    const unsigned short* __restrict__ eap, const float* __restrict__ al_s,
    const float* __restrict__ al_d, const int* __restrict__ srcp,
    const int* __restrict__ dstp, const float* __restrict__ we_att,
    float* __restrict__ abuf, int E){
  __shared__ float4 swe[EFEAT];
  int t = threadIdx.x;
  if (t < EFEAT) swe[t] = *(const float4*)&we_att[t*4];
  __syncthreads();
  int p = blockIdx.x*256 + t;
  if (p >= E) return;
  int s = srcp[p], d = dstp[p];
  float4 as = *(const float4*)&al_s[(size_t)s*4];
  float4 ad = *(const float4*)&al_d[(size_t)d*4];
  float a0 = as.x + ad.x, a1 = as.y + ad.y, a2 = as.z + ad.z, a3 = as.w + ad.w;
  const uint4* ep = (const uint4*)(eap + (size_t)p*EFEAT);
  #pragma unroll
  for (int q = 0; q < 4; q++){
    uint4 u = ep[q];
    unsigned arr[4] = {u.x, u.y, u.z, u.w};
    #pragma unroll
    for (int j = 0; j < 4; j++){
      float x0 = bf2f((unsigned short)(arr[j] & 0xffff));
      float x1 = bf2f((unsigned short)(arr[j] >> 16));
      float4 w0 = swe[q*8 + j*2], w1 = swe[q*8 + j*2 + 1];
      a0 += x0*w0.x + x1*w1.x;
      a1 += x0*w0.y + x1*w1.y;
      a2 += x0*w0.z + x1*w1.z;
      a3 += x0*w0.w + x1*w1.w;
    }
  }
  *(float4*)&abuf[(size_t)p*4] = make_float4(lrelu(a0), lrelu(a1), lrelu(a2), lrelu(a3));
}

// ---------------- fused softmax + aggregation (block per node, 64 threads) ------------
__global__ __launch_bounds__(64) void aggregate3_kernel(
    const unsigned short* __restrict__ hm_bf, const float* __restrict__ abuf,
    const float* __restrict__ al_s, const float* __restrict__ al_d,
    const float* __restrict__ al_self4, const int* __restrict__ offs,
    const int* __restrict__ srcp, unsigned short* __restrict__ z, int N){
  int n = blockIdx.x, t = threadIdx.x;
  int beg = offs[n], end = offs[n + 1];
  float4 aslf = *(const float4*)al_self4;
  float4 asn = *(const float4*)&al_s[(size_t)n*4];
  float4 adn = *(const float4*)&al_d[(size_t)n*4];
  float s0 = lrelu(asn.x + adn.x + aslf.x);
  float s1 = lrelu(asn.y + adn.y + aslf.y);
  float s2 = lrelu(asn.z + adn.z + aslf.z);
  float s3 = lrelu(asn.w + adn.w + aslf.w);
  float m0 = s0, m1 = s1, m2 = s2, m3 = s3;
  for (int p = beg + t; p < end; p += 64){
    float4 a = *(const float4*)&abuf[(size_t)p*4];
    m0 = fmaxf(m0, a.x); m1 = fmaxf(m1, a.y);
    m2 = fmaxf(m2, a.z); m3 = fmaxf(m3, a.w);
  }
  m0 = waveReduceMax(m0); m1 = waveReduceMax(m1);
  m2 = waveReduceMax(m2); m3 = waveReduceMax(m3);
  float e0 = __expf(s0 - m0), e1 = __expf(s1 - m1);
  float e2 = __expf(s2 - m2), e3 = __expf(s3 - m3);
  ushort2 hv = *((const ushort2*)(hm_bf + (size_t)n*DD) + t);
  float h0 = bf2f(hv.x), h1 = bf2f(hv.y);
  float ac00 = e0*h0, ac01 = e0*h1;
  float ac10 = e1*h0, ac11 = e1*h1;
  float ac20 = e2*h0, ac21 = e2*h1;
  float ac30 = e3*h0, ac31 = e3*h1;
  float den0 = e0, den1 = e1, den2 = e2, den3 = e3;
  int p = beg;
  for (; p + 2 <= end; p += 2){
    int sA = srcp[p], sB = srcp[p + 1];
    float4 aA = *(const float4*)&abuf[(size_t)p*4];
    float4 aB = *(const float4*)&abuf[(size_t)(p + 1)*4];
    ushort2 vA = *((const ushort2*)(hm_bf + (size_t)sA*DD) + t);
    ushort2 vB = *((const ushort2*)(hm_bf + (size_t)sB*DD) + t);
    float wA0 = __expf(aA.x - m0), wA1 = __expf(aA.y - m1);
    float wA2 = __expf(aA.z - m2), wA3 = __expf(aA.w - m3);
    float wB0 = __expf(aB.x - m0), wB1 = __expf(aB.y - m1);
    float wB2 = __expf(aB.z - m2), wB3 = __expf(aB.w - m3);
    float vA0 = bf2f(vA.x), vA1 = bf2f(vA.y);
    float vB0 = bf2f(vB.x), vB1 = bf2f(vB.y);
    ac00 += wA0*vA0 + wB0*vB0; ac01 += wA0*vA1 + wB0*vB1;
    ac10 += wA1*vA0 + wB1*vB0; ac11 += wA1*vA1 + wB1*vB1;
    ac20 += wA2*vA0 + wB2*vB0; ac21 += wA2*vA1 + wB2*vB1;
    ac30 += wA3*vA0 + wB3*vB0; ac31 += wA3*vA1 + wB3*vB1;
    den0 += wA0 + wB0; den1 += wA1 + wB1;
    den2 += wA2 + wB2; den3 += wA3 + wB3;
  }
  if (p < end){
    int s = srcp[p];
    float4 a = *(const float4*)&abuf[(size_t)p*4];
    ushort2 v2 = *((const ushort2*)(hm_bf + (size_t)s*DD) + t);
    float w0 = __expf(a.x - m0), w1 = __expf(a.y - m1);
    float w2 = __expf(a.z - m2), w3 = __expf(a.w - m3);
    float v0 = bf2f(v2.x), v1 = bf2f(v2.y);
    ac00 += w0*v0; ac01 += w0*v1;
    ac10 += w1*v0; ac11 += w1*v1;
    ac20 += w2*v0; ac21 += w2*v1;
    ac30 += w3*v0; ac31 += w3*v1;
    den0 += w0; den1 += w1; den2 += w2; den3 += w3;
  }
  float r0 = 1.f/(den0 + 1e-16f), r1 = 1.f/(den1 + 1e-16f);
  float r2 = 1.f/(den2 + 1e-16f), r3 = 1.f/(den3 + 1e-16f);
  size_t zb = (size_t)n*HDIM;
  ushort2* zp = (ushort2*)(z + zb);
  zp[0*64 + t] = make_ushort2(f2bf(ac00*r0), f2bf(ac01*r0));
  zp[1*64 + t] = make_ushort2(f2bf(ac10*r1), f2bf(ac11*r1));
  zp[2*64 + t] = make_ushort2(f2bf(ac20*r2), f2bf(ac21*r2));
  zp[3*64 + t] = make_ushort2(f2bf(ac30*r3), f2bf(ac31*r3));
}

// ---------------- MFMA edge head: out[e] = relu(p[s]+p[d]+ea@W1c)@W2 + b2 ------------
// pbuf: [N,256] bf16, cols 0-127 = p_src (hB1 folded), 128-255 = p_dst
__global__ __launch_bounds__(256) void head_mfma_kernel(
    const unsigned short* __restrict__ eap, const int* __restrict__ posOf,
    const unsigned short* __restrict__ Bh, const unsigned short* __restrict__ pbuf,
    const float* __restrict__ W2, const float* __restrict__ b2,
    const int* __restrict__ srcA, const int* __restrict__ dstA,
    float* __restrict__ out, int E){
  int t = threadIdx.x;
  int wave = t >> 6, lane = t & 63;
  int ln15 = lane & 15, quad = lane >> 4;
  int e0 = (blockIdx.x*4 + wave)*16;
  if (e0 >= E) return;
  int arow = e0 + ln15;
  if (arow > E - 1) arow = E - 1;
  int ap = posOf[arow];
  s16x8 a = *(const s16x8*)(eap + (size_t)ap*EFEAT + quad*8);
  f32x4 acc[8];
  #pragma unroll
  for (int c = 0; c < 8; c++){
    s16x8 b = *(const s16x8*)(Bh + ((size_t)c*64 + lane)*8);
    acc[c] = __builtin_amdgcn_mfma_f32_16x16x32_bf16(a, b, (f32x4)(0.f), 0, 0, 0);
  }
  float w2v[8];
  #pragma unroll
  for (int c = 0; c < 8; c++) w2v[c] = W2[c*16 + ln15];
  float res[4];
  #pragma unroll
  for (int r = 0; r < 4; r++){
    int e = e0 + quad*4 + r;
    int ec = (e < E) ? e : E - 1;
    int s = srcA[ec], d = dstA[ec];
    const unsigned short* ps = pbuf + (size_t)s*256 + ln15;
    const unsigned short* pd = pbuf + (size_t)d*256 + 128 + ln15;
    float sum = 0.f;
    #pragma unroll
    for (int c = 0; c < 8; c++){
      float q = acc[c][r] + bf2f(ps[c*16]) + bf2f(pd[c*16]);
      sum += fmaxf(q, 0.f) * w2v[c];
    }
    res[r] = sum;
  }
  #pragma unroll
  for (int r = 0; r < 4; r++){
    float v = res[r];
    v += __shfl_xor(v, 1, 64); v += __shfl_xor(v, 2, 64);
    v += __shfl_xor(v, 4, 64); v += __shfl_xor(v, 8, 64);
    res[r] = v;
  }
  if (ln15 == 0){
    float bb = b2[0];
    #pragma unroll
    for (int r = 0; r < 4; r++){
      int e = e0 + quad*4 + r;
      if (e < E) out[e] = res[r] + bb;
    }
  }
}

extern "C" void kernel_launch(void* const* d_in, const int* in_sizes, int n_in,
                              void* d_out, int out_size, void* d_ws, size_t ws_size,
                              hipStream_t stream){
  const float* x      = (const float*)d_in[0];
  const int*   eidx   = (const int*)d_in[1];
  const float* eattr  = (const float*)d_in[2];
  const float* gamma  = (const float*)d_in[3];
  const float* beta   = (const float*)d_in[4];
  const float* embW   = (const float*)d_in[5];
  const float* embB   = (const float*)d_in[6];
  const float* lnS    = (const float*)d_in[7];
  const float* lnB    = (const float*)d_in[8];
  const float* gatW   = (const float*)d_in[9];
  const float* attS   = (const float*)d_in[10];
  const float* attD   = (const float*)d_in[11];
  const float* gatWe  = (const float*)d_in[12];
  const float* attE   = (const float*)d_in[13];
  const float* gatB   = (const float*)d_in[14];
  const float* hW1    = (const float*)d_in[15];
  const float* hB1    = (const float*)d_in[16];
  const float* hW2    = (const float*)d_in[17];
  const float* hB2    = (const float*)d_in[18];
  float* out = (float*)d_out;

  int N = in_sizes[0] / DD;
  int E = in_sizes[1] / 2;
  int L = in_sizes[3] / DD;
  int Npad = (N + 63) & ~63;

  const int* srcA = eidx;
  const int* dstA = eidx + E;

  float* ws = (float*)d_ws;
  float* ea_sum  = ws + 0;
  float* we_att  = ws + 64;
  float* al_self = ws + 1024;
  float* ws_att  = ws + 2048;
  size_t o = 8192;
  int* deg    = (int*)(ws + o); o += N;
  int* offs   = (int*)(ws + o); o += N + 1;
  int* cursor = (int*)(ws + o); o += N;
  int* eid    = (int*)(ws + o); o += E;
  int* srcp   = (int*)(ws + o); o += E;
  int* dstp   = (int*)(ws + o); o += E;
  int* posOf  = (int*)(ws + o); o += E;
  o = (o + 255) & ~(size_t)255;
  unsigned short* Bt  = (unsigned short*)(ws + o); o += (size_t)L*DD*HDIM/2;
  unsigned short* Bh  = (unsigned short*)(ws + o); o += 8*64*8/2;
  unsigned short* Wte = (unsigned short*)(ws + o); o += DD*DD/2;      // embW^T bf16
  unsigned short* Bhd = (unsigned short*)(ws + o); o += 256*DD/2;     // [W1a|W1b]^T bf16
  unsigned short* xbf = (unsigned short*)(ws + o); o += (size_t)N*DD/2;
  unsigned short* hm_bf = (unsigned short*)(ws + o); o += (size_t)N*DD/2;
  float* al_s  = ws + o; o += (size_t)N*4;
  float* al_d  = ws + o; o += (size_t)N*4;
  unsigned short* eap = (unsigned short*)(ws + o); o += (size_t)E*EFEAT/2;
  float* abuf  = ws + o; o += (size_t)E*4;
  unsigned short* z = (unsigned short*)(ws + o); o += (size_t)Npad*HDIM/2;
  // reuse: hbf (final h, bf16) lives in hm_bf (dead after last aggregate);
  // pbuf [N,256] bf16 lives in z (dead after final gemm)
  unsigned short* hbf  = hm_bf;
  unsigned short* pbuf = z;

  hipMemsetAsync(ea_sum, 0, EFEAT*sizeof(float), stream);
  hipMemsetAsync(deg, 0, (size_t)N*sizeof(int), stream);
  ea_sum4_kernel<<<1024, 256, 0, stream>>>(eattr, ea_sum, E);
  hist_kernel<<<(E + 255)/256, 256, 0, stream>>>(dstA, deg, E);
  scan_kernel<<<1, 1024, 0, stream>>>(deg, offs, N);
  hipMemcpyAsync(cursor, offs, (size_t)N*sizeof(int), hipMemcpyDeviceToDevice, stream);
  scatter_kernel<<<(E + 255)/256, 256, 0, stream>>>(dstA, srcA, cursor, eid, srcp, dstp,
                                                    posOf, E);
  eap_prep_kernel<<<(E*8 + 255)/256, 256, 0, stream>>>(eattr, eid, eap, E);
  fold_ws_kernel<<<(L*DD*8 + 3)/4, 256, 0, stream>>>(gatW, attS, attD, ws_att, L);
  fold_we_kernel<<<(L*EFEAT*NHEAD + 3)/4, 256, 0, stream>>>(gatWe, attE, we_att, L);
  fold_self_kernel<<<1, 64, 0, stream>>>(we_att, ea_sum, 1.0f/(float)E, al_self, L);
  bt_prep_kernel<<<(L*DD*HDIM + 255)/256, 256, 0, stream>>>(gatW, Bt, L*DD*HDIM);
  embwt_prep_kernel<<<(DD*DD + 255)/256, 256, 0, stream>>>(embW, Wte);
  w1ab_prep_kernel<<<(256*DD + 255)/256, 256, 0, stream>>>(hW1, Bhd);
  w1c_prep_kernel<<<(8*64*8 + 255)/256, 256, 0, stream>>>(hW1 + 2*DD*DD, Bh);
  bf16_conv_kernel<<<(N*DD/4 + 255)/256, 256, 0, stream>>>(x, xbf, N*DD/4);

  // embed + LN/FiLM/al (layer 0)
  gemm_fused_kernel<128,128><<<(N + 63)/64, 256, 0, stream>>>(
      xbf, Wte, embB, 1.0f, 0, 0, lnS, lnB, gamma, beta, ws_att,
      hm_bf, al_s, al_d, nullptr, N);

  for (int l = 0; l < L; l++){
    edge_logit_kernel<<<(E + 255)/256, 256, 0, stream>>>(eap, al_s, al_d, srcp, dstp,
        we_att + (size_t)l*EFEAT*NHEAD, abuf, E);
    aggregate3_kernel<<<N, 64, 0, stream>>>(hm_bf, abuf, al_s, al_d,
        al_self + (size_t)l*NHEAD, offs, srcp, z, N);
    if (l < L - 1){
      gemm_fused_kernel<512,128><<<(N + 63)/64, 256, 0, stream>>>(
          z, Bt + (size_t)l*DD*HDIM, gatB + (size_t)l*DD, 0.25f, 1, 0,
          lnS + (l+1)*DD, lnB + (l+1)*DD, gamma + (l+1)*DD, beta + (l+1)*DD,
          ws_att + (size_t)(l+1)*DD*8, hm_bf, al_s, al_d, nullptr, N);
    } else {
      gemm_fused_kernel<512,128><<<(N + 63)/64, 256, 0, stream>>>(
          z, Bt + (size_t)l*DD*HDIM, gatB + (size_t)l*DD, 0.25f, 1, 1,
          nullptr, nullptr, nullptr, nullptr, nullptr,
          nullptr, nullptr, nullptr, hbf, N);
    }
  }

  // head pre-projection: pbuf[N,256] = hbf @ [W1a|W1b] (+hB1 on cols<128)
  gemm_fused_kernel<128,256><<<(N + 63)/64, 256, 0, stream>>>(
      hbf, Bhd, hB1, 1.0f, 0, 1, nullptr, nullptr, nullptr, nullptr, nullptr,
      nullptr, nullptr, nullptr, pbuf, N);

  head_mfma_kernel<<<(E + 63)/64, 256, 0, stream>>>(eap, posOf, Bh, pbuf,
      hW2, hB2, srcA, dstA, out, E);
}